// Round 1
// baseline (1624.727 us; speedup 1.0000x reference)
//
#include <hip/hip_runtime.h>
#include <hip/hip_bf16.h>
#include <cstddef>

// Problem constants
constexpr int NL = 2, DM = 512, DI = 1024, DS = 8, DC = 4, DTR = 32, NC = 50;
constexpr int B = 4, L = 2048;
constexpr int M = B * L;          // 8192 rows
constexpr int XZW = 2 * DI;       // 2048
constexpr int XDW = DTR + 2 * DS; // 48
constexpr int NCH = 64, CH = L / NCH; // chunked scan: 64 chunks of 32

// ---------------- embed: h[b,l,d] = x[b,0,l]*inp_w[d,0] + inp_b[d] ----------
__global__ void embed_k(const float* __restrict__ x, const float* __restrict__ iw,
                        const float* __restrict__ ib, float* __restrict__ h) {
    int idx = blockIdx.x * blockDim.x + threadIdx.x;
    if (idx >= M * DM) return;
    int d = idx % DM;
    int m = idx / DM;
    h[idx] = x[m] * iw[d] + ib[d];
}

// ---------------- layernorm over last dim (DM=512), one block per row -------
__global__ __launch_bounds__(256) void layernorm_k(const float* __restrict__ in,
                                                   const float* __restrict__ g,
                                                   const float* __restrict__ b,
                                                   float* __restrict__ out) {
    int row = blockIdx.x;
    const float* x = in + (size_t)row * DM;
    int t = threadIdx.x;
    float v0 = x[t], v1 = x[t + 256];
    float s = v0 + v1, sq = v0 * v0 + v1 * v1;
    for (int o = 32; o > 0; o >>= 1) {
        s += __shfl_down(s, o);
        sq += __shfl_down(sq, o);
    }
    __shared__ float sums[8];
    if ((t & 63) == 0) { sums[t >> 6] = s; sums[4 + (t >> 6)] = sq; }
    __syncthreads();
    float tot = sums[0] + sums[1] + sums[2] + sums[3];
    float totq = sums[4] + sums[5] + sums[6] + sums[7];
    float mu = tot * (1.0f / DM);
    float var = totq * (1.0f / DM) - mu * mu;
    float rs = rsqrtf(var + 1e-5f);
    out[(size_t)row * DM + t]       = (v0 - mu) * rs * g[t] + b[t];
    out[(size_t)row * DM + t + 256] = (v1 - mu) * rs * g[t + 256] + b[t + 256];
}

// ---------------- generic fp32 tiled GEMM: C[m,n] = sum_k A[m,k]*W[n,k] -----
// EPI: 0 = store, 1 = accumulate (C += acc), 2 = softplus(acc + bias[n])
template <int EPI>
__global__ __launch_bounds__(256) void gemm_nt(const float* __restrict__ A, int lda,
                                               const float* __restrict__ W,
                                               const float* __restrict__ bias,
                                               float* __restrict__ C,
                                               int Mr, int Nr, int K) {
    constexpr int BMt = 64, BNt = 64, BKt = 16;
    __shared__ float As[BMt][BKt];
    __shared__ float Ws[BKt][BNt];
    int tid = threadIdx.x;
    int tx = tid % 16, ty = tid / 16;
    int m0 = blockIdx.y * BMt, n0 = blockIdx.x * BNt;
    float acc[4][4] = {};
    int arow = tid / 4;          // 0..63
    int akb = (tid % 4) * 4;     // 0,4,8,12

    for (int k0 = 0; k0 < K; k0 += BKt) {
        float4 av = *reinterpret_cast<const float4*>(A + (size_t)(m0 + arow) * lda + k0 + akb);
        *reinterpret_cast<float4*>(&As[arow][akb]) = av;
        float4 wv = make_float4(0.f, 0.f, 0.f, 0.f);
        if (n0 + arow < Nr)
            wv = *reinterpret_cast<const float4*>(W + (size_t)(n0 + arow) * K + k0 + akb);
        Ws[akb + 0][arow] = wv.x;
        Ws[akb + 1][arow] = wv.y;
        Ws[akb + 2][arow] = wv.z;
        Ws[akb + 3][arow] = wv.w;
        __syncthreads();
#pragma unroll
        for (int kk = 0; kk < BKt; ++kk) {
            float a[4], bb[4];
#pragma unroll
            for (int i = 0; i < 4; i++) a[i] = As[ty * 4 + i][kk];
#pragma unroll
            for (int j = 0; j < 4; j++) bb[j] = Ws[kk][tx * 4 + j];
#pragma unroll
            for (int i = 0; i < 4; i++)
#pragma unroll
                for (int j = 0; j < 4; j++) acc[i][j] += a[i] * bb[j];
        }
        __syncthreads();
    }
#pragma unroll
    for (int i = 0; i < 4; i++) {
        int row = m0 + ty * 4 + i;
        if (row >= Mr) continue;
#pragma unroll
        for (int j = 0; j < 4; j++) {
            int col = n0 + tx * 4 + j;
            if (col >= Nr) continue;
            size_t idx = (size_t)row * Nr + col;
            if (EPI == 0) {
                C[idx] = acc[i][j];
            } else if (EPI == 1) {
                C[idx] += acc[i][j];
            } else {
                float v = acc[i][j] + bias[col];
                C[idx] = (v > 20.0f) ? v : log1pf(expf(v));
            }
        }
    }
}

// ---------------- causal depthwise conv (DC=4) + SiLU -----------------------
__global__ void conv_silu_k(const float* __restrict__ xz, const float* __restrict__ cw,
                            const float* __restrict__ cb, float* __restrict__ uc) {
    int idx = blockIdx.x * blockDim.x + threadIdx.x;
    if (idx >= M * DI) return;
    int d = idx % DI;
    int m = idx / DI;
    int b = m / L, l = m % L;
    float acc = cb[d];
#pragma unroll
    for (int k = 0; k < DC; k++) {
        int ls = l + k - (DC - 1);
        if (ls >= 0) acc += xz[(size_t)(b * L + ls) * XZW + d] * cw[d * DC + k];
    }
    uc[idx] = acc / (1.0f + expf(-acc));
}

// ---------------- selective scan, 3-phase chunked ---------------------------
// phase 1: per (b,d,chunk) compute within-chunk partial (h from 0) and dA cumprod
__global__ __launch_bounds__(256) void scan_part_k(const float* __restrict__ dt,
                                                   const float* __restrict__ uc,
                                                   const float* __restrict__ xdbl,
                                                   const float* __restrict__ A_log,
                                                   float* __restrict__ hpart,
                                                   float* __restrict__ aprod) {
    int gid = blockIdx.x * 256 + threadIdx.x;
    if (gid >= B * NCH * DI) return;
    int d = gid % DI;
    int c = (gid / DI) % NCH;
    int b = gid / (DI * NCH);
    float Av[DS];
#pragma unroll
    for (int n = 0; n < DS; n++) Av[n] = -expf(A_log[d * DS + n]);
    float h[DS] = {};
    float ap[DS];
#pragma unroll
    for (int n = 0; n < DS; n++) ap[n] = 1.0f;
    int l0 = c * CH;
    for (int t = 0; t < CH; t++) {
        size_t row = (size_t)b * L + l0 + t;
        float dtv = dt[row * DI + d];
        float uv = uc[row * DI + d];
        const float* xr = xdbl + row * XDW;
        float du = dtv * uv;
#pragma unroll
        for (int n = 0; n < DS; n++) {
            float dA = expf(dtv * Av[n]);
            h[n] = dA * h[n] + du * xr[DTR + n];
            ap[n] *= dA;
        }
    }
    size_t base = (((size_t)b * DI + d) * NCH + c) * DS;
#pragma unroll
    for (int n = 0; n < DS; n++) {
        hpart[base + n] = h[n];
        aprod[base + n] = ap[n];
    }
}

// phase 2: per (b,d), sequential combine over chunks; hpart[c] := state BEFORE chunk c
__global__ void scan_combine_k(float* __restrict__ hpart, const float* __restrict__ aprod) {
    int gid = blockIdx.x * blockDim.x + threadIdx.x;
    if (gid >= B * DI) return;
    float hrun[DS] = {};
    size_t base0 = (size_t)gid * NCH * DS;
    for (int c = 0; c < NCH; c++) {
        size_t base = base0 + (size_t)c * DS;
#pragma unroll
        for (int n = 0; n < DS; n++) {
            float ap = aprod[base + n];
            float hp = hpart[base + n];
            hpart[base + n] = hrun[n];
            hrun[n] = ap * hrun[n] + hp;
        }
    }
}

// phase 3: re-emit with correct incoming state; fuse y = C.h + u*D, y *= silu(z)
__global__ __launch_bounds__(256) void scan_emit_k(const float* __restrict__ dt,
                                                   const float* __restrict__ uc,
                                                   const float* __restrict__ xdbl,
                                                   const float* __restrict__ xz,
                                                   const float* __restrict__ A_log,
                                                   const float* __restrict__ Dp,
                                                   const float* __restrict__ hpart,
                                                   float* __restrict__ y) {
    int gid = blockIdx.x * 256 + threadIdx.x;
    if (gid >= B * NCH * DI) return;
    int d = gid % DI;
    int c = (gid / DI) % NCH;
    int b = gid / (DI * NCH);
    float Av[DS];
#pragma unroll
    for (int n = 0; n < DS; n++) Av[n] = -expf(A_log[d * DS + n]);
    float h[DS];
    size_t sbase = (((size_t)b * DI + d) * NCH + c) * DS;
#pragma unroll
    for (int n = 0; n < DS; n++) h[n] = hpart[sbase + n];
    float Dv = Dp[d];
    int l0 = c * CH;
    for (int t = 0; t < CH; t++) {
        size_t row = (size_t)b * L + l0 + t;
        float dtv = dt[row * DI + d];
        float uv = uc[row * DI + d];
        const float* xr = xdbl + row * XDW;
        float du = dtv * uv;
        float yv = 0.f;
#pragma unroll
        for (int n = 0; n < DS; n++) {
            float dA = expf(dtv * Av[n]);
            h[n] = dA * h[n] + du * xr[DTR + n];
            yv += h[n] * xr[DTR + DS + n];
        }
        yv += uv * Dv;
        float zv = xz[row * XZW + DI + d];
        yv *= zv / (1.0f + expf(-zv));
        y[row * DI + d] = yv;
    }
}

// ---------------- mean over L, then head -----------------------------------
__global__ void mean_k(const float* __restrict__ hn, float* __restrict__ hmean) {
    int idx = blockIdx.x * blockDim.x + threadIdx.x;
    if (idx >= B * DM) return;
    int d = idx % DM, b = idx / DM;
    float s = 0.f;
    for (int l = 0; l < L; l++) s += hn[(size_t)(b * L + l) * DM + d];
    hmean[idx] = s * (1.0f / L);
}

__global__ void head_k(const float* __restrict__ hmean, const float* __restrict__ hw,
                       const float* __restrict__ hb, float* __restrict__ out) {
    int t = threadIdx.x;
    if (t >= B * NC) return;
    int b = t / NC, c = t % NC;
    float acc = hb[c];
    for (int k = 0; k < DM; k++) acc += hmean[b * DM + k] * hw[c * DM + k];
    out[t] = acc;
}

extern "C" void kernel_launch(void* const* d_in, const int* in_sizes, int n_in,
                              void* d_out, int out_size, void* d_ws, size_t ws_size,
                              hipStream_t stream) {
    const float* x      = (const float*)d_in[0];
    const float* inp_w  = (const float*)d_in[1];
    const float* inp_b  = (const float*)d_in[2];
    const float* norm_g = (const float*)d_in[3];
    const float* norm_b = (const float*)d_in[4];
    const float* in_w   = (const float*)d_in[5];
    const float* conv_w = (const float*)d_in[6];
    const float* conv_b = (const float*)d_in[7];
    const float* xp_w   = (const float*)d_in[8];
    const float* dt_w   = (const float*)d_in[9];
    const float* dt_b   = (const float*)d_in[10];
    const float* A_log  = (const float*)d_in[11];
    const float* Dp     = (const float*)d_in[12];
    const float* out_w  = (const float*)d_in[13];
    const float* fnorm_g = (const float*)d_in[14];
    const float* fnorm_b = (const float*)d_in[15];
    const float* head_w = (const float*)d_in[16];
    const float* head_b = (const float*)d_in[17];
    float* out = (float*)d_out;

    float* ws = (float*)d_ws;
    float* h     = ws;
    float* hn    = h + (size_t)M * DM;
    float* xz    = hn + (size_t)M * DM;
    float* uc    = xz + (size_t)M * XZW;
    float* xdbl  = uc + (size_t)M * DI;
    float* dtb   = xdbl + (size_t)M * XDW;
    float* yb    = dtb + (size_t)M * DI;
    float* hpart = yb + (size_t)M * DI;
    float* aprod = hpart + (size_t)B * DI * NCH * DS;
    float* hmean = aprod + (size_t)B * DI * NCH * DS;

    // embed
    embed_k<<<(M * DM + 255) / 256, 256, 0, stream>>>(x, inp_w, inp_b, h);

    for (int i = 0; i < NL; i++) {
        const float* inw_i = in_w + (size_t)i * XZW * DM;
        const float* cw_i  = conv_w + (size_t)i * DI * DC;
        const float* cb_i  = conv_b + (size_t)i * DI;
        const float* xpw_i = xp_w + (size_t)i * XDW * DI;
        const float* dtw_i = dt_w + (size_t)i * DI * DTR;
        const float* dtb_i = dt_b + (size_t)i * DI;
        const float* Al_i  = A_log + (size_t)i * DI * DS;
        const float* Dp_i  = Dp + (size_t)i * DI;
        const float* ow_i  = out_w + (size_t)i * DM * DI;

        // hn = LN(h)
        layernorm_k<<<M, 256, 0, stream>>>(h, norm_g + i * DM, norm_b + i * DM, hn);
        // xz = hn @ in_w^T   (M x 2048, K=512)
        gemm_nt<0><<<dim3(XZW / 64, M / 64), 256, 0, stream>>>(hn, DM, inw_i, nullptr, xz, M, XZW, DM);
        // uc = silu(conv(u))
        conv_silu_k<<<(M * DI + 255) / 256, 256, 0, stream>>>(xz, cw_i, cb_i, uc);
        // xdbl = uc @ xp_w^T  (M x 48, K=1024)
        gemm_nt<0><<<dim3(1, M / 64), 256, 0, stream>>>(uc, DI, xpw_i, nullptr, xdbl, M, XDW, DI);
        // dt = softplus(xdbl[:, :32] @ dt_w^T + dt_b)  (M x 1024, K=32, lda=48)
        gemm_nt<2><<<dim3(DI / 64, M / 64), 256, 0, stream>>>(xdbl, XDW, dtw_i, dtb_i, dtb, M, DI, DTR);
        // selective scan (chunked), fused gate + u*D
        scan_part_k<<<(B * NCH * DI) / 256, 256, 0, stream>>>(dtb, uc, xdbl, Al_i, hpart, aprod);
        scan_combine_k<<<(B * DI + 255) / 256, 256, 0, stream>>>(hpart, aprod);
        scan_emit_k<<<(B * NCH * DI) / 256, 256, 0, stream>>>(dtb, uc, xdbl, xz, Al_i, Dp_i, hpart, yb);
        // h += y @ out_w^T  (M x 512, K=1024)
        gemm_nt<1><<<dim3(DM / 64, M / 64), 256, 0, stream>>>(yb, DI, ow_i, nullptr, h, M, DM, DI);
    }

    // final LN -> mean over L -> head
    layernorm_k<<<M, 256, 0, stream>>>(h, fnorm_g, fnorm_b, hn);
    mean_k<<<(B * DM + 255) / 256, 256, 0, stream>>>(hn, hmean);
    head_k<<<1, 256, 0, stream>>>(hmean, head_w, head_b, out);
}

// Round 2
// 1001.276 us; speedup vs baseline: 1.6227x; 1.6227x over previous
//
#include <hip/hip_runtime.h>
#include <hip/hip_bf16.h>
#include <cstddef>

// Problem constants
constexpr int NL = 2, DM = 512, DI = 1024, DS = 8, DC = 4, DTR = 32, NC = 50;
constexpr int B = 4, L = 2048;
constexpr int M = B * L;          // 8192 rows
constexpr int XZW = 2 * DI;       // 2048
constexpr int XDW = DTR + 2 * DS; // 48
constexpr int NCH = 64, CH = L / NCH; // chunked scan: 64 chunks of 32

typedef __bf16 bf16_t;
typedef bf16_t bf16x8 __attribute__((ext_vector_type(8)));
typedef float f32x4 __attribute__((ext_vector_type(4)));

// ---------------- embed: h[b,l,d] = x[b,0,l]*inp_w[d,0] + inp_b[d] ----------
__global__ void embed_k(const float* __restrict__ x, const float* __restrict__ iw,
                        const float* __restrict__ ib, float* __restrict__ h) {
    int idx = blockIdx.x * blockDim.x + threadIdx.x;
    if (idx >= M * DM) return;
    int d = idx % DM;
    int m = idx / DM;
    h[idx] = x[m] * iw[d] + ib[d];
}

// ---------------- layernorm over last dim (DM=512), one block per row -------
__global__ __launch_bounds__(256) void layernorm_k(const float* __restrict__ in,
                                                   const float* __restrict__ g,
                                                   const float* __restrict__ b,
                                                   float* __restrict__ out) {
    int row = blockIdx.x;
    const float* x = in + (size_t)row * DM;
    int t = threadIdx.x;
    float v0 = x[t], v1 = x[t + 256];
    float s = v0 + v1, sq = v0 * v0 + v1 * v1;
    for (int o = 32; o > 0; o >>= 1) {
        s += __shfl_down(s, o);
        sq += __shfl_down(sq, o);
    }
    __shared__ float sums[8];
    if ((t & 63) == 0) { sums[t >> 6] = s; sums[4 + (t >> 6)] = sq; }
    __syncthreads();
    float tot = sums[0] + sums[1] + sums[2] + sums[3];
    float totq = sums[4] + sums[5] + sums[6] + sums[7];
    float mu = tot * (1.0f / DM);
    float var = totq * (1.0f / DM) - mu * mu;
    float rs = rsqrtf(var + 1e-5f);
    out[(size_t)row * DM + t]       = (v0 - mu) * rs * g[t] + b[t];
    out[(size_t)row * DM + t + 256] = (v1 - mu) * rs * g[t + 256] + b[t + 256];
}

// ---------------- bf16 MFMA GEMM: C[m,n] (+)= sum_k A[m,k]*W[n,k] ----------
// A fp32 (lda), W fp32 (ldw) -> converted to bf16 in-register while staging.
// EPI: 0 = store, 1 = accumulate (C += acc), 2 = softplus(acc + bias[n])
// 256 threads = 4 waves in 2x2. BK = 32.
template <int BM, int BN, int EPI>
__global__ __launch_bounds__(256) void gemm_mfma(const float* __restrict__ A, int lda,
                                                 const float* __restrict__ W, int ldw,
                                                 const float* __restrict__ bias,
                                                 float* __restrict__ C, int ldc,
                                                 int Nr, int K) {
    constexpr int WM = BM / 2, WN = BN / 2;
    constexpr int FM = WM / 16, FN = WN / 16;
    constexpr int ACH = BM * 32 / (256 * 8);   // 8-elem granules per thread (A)
    constexpr int WCH = BN * 32 / (256 * 8);   // (W)
    __shared__ bf16_t As[BM * 32];
    __shared__ bf16_t Ws[BN * 32];

    int t = threadIdx.x;
    int m0 = blockIdx.y * BM, n0 = blockIdx.x * BN;
    int wave = t >> 6, lane = t & 63;
    int wr = wave >> 1, wc = wave & 1;
    int lr = lane & 15, lk = lane >> 4;

    f32x4 acc[FM][FN];
#pragma unroll
    for (int i = 0; i < FM; i++)
#pragma unroll
        for (int j = 0; j < FN; j++)
#pragma unroll
            for (int q = 0; q < 4; q++) acc[i][j][q] = 0.0f;

    for (int k0 = 0; k0 < K; k0 += 32) {
        __syncthreads();
        // stage A tile: rows m0..m0+BM-1, k0..k0+31, fp32 -> bf16, swizzled 16B slots
#pragma unroll
        for (int c = 0; c < ACH; ++c) {
            int e = t + c * 256;
            int r = e >> 2;        // local row
            int g = e & 3;         // 8-elem granule within the 32-wide row
            const float* src = A + (size_t)(m0 + r) * lda + k0 + g * 8;
            float4 f0 = *reinterpret_cast<const float4*>(src);
            float4 f1 = *reinterpret_cast<const float4*>(src + 4);
            bf16x8 v;
            v[0] = (bf16_t)f0.x; v[1] = (bf16_t)f0.y; v[2] = (bf16_t)f0.z; v[3] = (bf16_t)f0.w;
            v[4] = (bf16_t)f1.x; v[5] = (bf16_t)f1.y; v[6] = (bf16_t)f1.z; v[7] = (bf16_t)f1.w;
            int slot = g ^ ((r >> 1) & 3);
            *reinterpret_cast<bf16x8*>(&As[r * 32 + slot * 8]) = v;
        }
        // stage W tile: rows n0..n0+BN-1 (guarded), same layout
#pragma unroll
        for (int c = 0; c < WCH; ++c) {
            int e = t + c * 256;
            int r = e >> 2;
            int g = e & 3;
            bf16x8 v;
#pragma unroll
            for (int q = 0; q < 8; q++) v[q] = (bf16_t)0.0f;
            if (n0 + r < Nr) {
                const float* src = W + (size_t)(n0 + r) * ldw + k0 + g * 8;
                float4 f0 = *reinterpret_cast<const float4*>(src);
                float4 f1 = *reinterpret_cast<const float4*>(src + 4);
                v[0] = (bf16_t)f0.x; v[1] = (bf16_t)f0.y; v[2] = (bf16_t)f0.z; v[3] = (bf16_t)f0.w;
                v[4] = (bf16_t)f1.x; v[5] = (bf16_t)f1.y; v[6] = (bf16_t)f1.z; v[7] = (bf16_t)f1.w;
            }
            int slot = g ^ ((r >> 1) & 3);
            *reinterpret_cast<bf16x8*>(&Ws[r * 32 + slot * 8]) = v;
        }
        __syncthreads();

        // fragment loads + MFMA
        bf16x8 af[FM], bf[FN];
#pragma unroll
        for (int mi = 0; mi < FM; mi++) {
            int r = wr * WM + mi * 16 + lr;
            int slot = lk ^ ((r >> 1) & 3);
            af[mi] = *reinterpret_cast<const bf16x8*>(&As[r * 32 + slot * 8]);
        }
#pragma unroll
        for (int ni = 0; ni < FN; ni++) {
            int r = wc * WN + ni * 16 + lr;
            int slot = lk ^ ((r >> 1) & 3);
            bf[ni] = *reinterpret_cast<const bf16x8*>(&Ws[r * 32 + slot * 8]);
        }
#pragma unroll
        for (int mi = 0; mi < FM; mi++)
#pragma unroll
            for (int ni = 0; ni < FN; ni++)
                acc[mi][ni] = __builtin_amdgcn_mfma_f32_16x16x32_bf16(af[mi], bf[ni], acc[mi][ni], 0, 0, 0);
    }

    // epilogue: C/D layout col=lane&15, row=(lane>>4)*4+reg
#pragma unroll
    for (int mi = 0; mi < FM; mi++) {
#pragma unroll
        for (int ni = 0; ni < FN; ni++) {
            int col = n0 + wc * WN + ni * 16 + lr;
            if (col >= Nr) continue;
#pragma unroll
            for (int i = 0; i < 4; i++) {
                int row = m0 + wr * WM + mi * 16 + lk * 4 + i;
                size_t idx = (size_t)row * ldc + col;
                float v = acc[mi][ni][i];
                if (EPI == 0) {
                    C[idx] = v;
                } else if (EPI == 1) {
                    C[idx] += v;
                } else {
                    float s = v + bias[col];
                    C[idx] = (s > 20.0f) ? s : log1pf(expf(s));
                }
            }
        }
    }
}

// ---------------- causal depthwise conv (DC=4) + SiLU -----------------------
__global__ void conv_silu_k(const float* __restrict__ xz, const float* __restrict__ cw,
                            const float* __restrict__ cb, float* __restrict__ uc) {
    int idx = blockIdx.x * blockDim.x + threadIdx.x;
    if (idx >= M * DI) return;
    int d = idx % DI;
    int m = idx / DI;
    int b = m / L, l = m % L;
    float acc = cb[d];
#pragma unroll
    for (int k = 0; k < DC; k++) {
        int ls = l + k - (DC - 1);
        if (ls >= 0) acc += xz[(size_t)(b * L + ls) * XZW + d] * cw[d * DC + k];
    }
    uc[idx] = acc / (1.0f + expf(-acc));
}

// ---------------- selective scan, 3-phase chunked ---------------------------
__global__ __launch_bounds__(256) void scan_part_k(const float* __restrict__ dt,
                                                   const float* __restrict__ uc,
                                                   const float* __restrict__ xdbl,
                                                   const float* __restrict__ A_log,
                                                   float* __restrict__ hpart,
                                                   float* __restrict__ aprod) {
    int gid = blockIdx.x * 256 + threadIdx.x;
    if (gid >= B * NCH * DI) return;
    int d = gid % DI;
    int c = (gid / DI) % NCH;
    int b = gid / (DI * NCH);
    float Av[DS];
#pragma unroll
    for (int n = 0; n < DS; n++) Av[n] = -expf(A_log[d * DS + n]);
    float h[DS] = {};
    float ap[DS];
#pragma unroll
    for (int n = 0; n < DS; n++) ap[n] = 1.0f;
    int l0 = c * CH;
    for (int t = 0; t < CH; t++) {
        size_t row = (size_t)b * L + l0 + t;
        float dtv = dt[row * DI + d];
        float uv = uc[row * DI + d];
        const float* xr = xdbl + row * XDW;
        float du = dtv * uv;
#pragma unroll
        for (int n = 0; n < DS; n++) {
            float dA = expf(dtv * Av[n]);
            h[n] = dA * h[n] + du * xr[DTR + n];
            ap[n] *= dA;
        }
    }
    size_t base = (((size_t)b * DI + d) * NCH + c) * DS;
#pragma unroll
    for (int n = 0; n < DS; n++) {
        hpart[base + n] = h[n];
        aprod[base + n] = ap[n];
    }
}

__global__ void scan_combine_k(float* __restrict__ hpart, const float* __restrict__ aprod) {
    int gid = blockIdx.x * blockDim.x + threadIdx.x;
    if (gid >= B * DI) return;
    float hrun[DS] = {};
    size_t base0 = (size_t)gid * NCH * DS;
    for (int c = 0; c < NCH; c++) {
        size_t base = base0 + (size_t)c * DS;
#pragma unroll
        for (int n = 0; n < DS; n++) {
            float ap = aprod[base + n];
            float hp = hpart[base + n];
            hpart[base + n] = hrun[n];
            hrun[n] = ap * hrun[n] + hp;
        }
    }
}

__global__ __launch_bounds__(256) void scan_emit_k(const float* __restrict__ dt,
                                                   const float* __restrict__ uc,
                                                   const float* __restrict__ xdbl,
                                                   const float* __restrict__ xz,
                                                   const float* __restrict__ A_log,
                                                   const float* __restrict__ Dp,
                                                   const float* __restrict__ hpart,
                                                   float* __restrict__ y) {
    int gid = blockIdx.x * 256 + threadIdx.x;
    if (gid >= B * NCH * DI) return;
    int d = gid % DI;
    int c = (gid / DI) % NCH;
    int b = gid / (DI * NCH);
    float Av[DS];
#pragma unroll
    for (int n = 0; n < DS; n++) Av[n] = -expf(A_log[d * DS + n]);
    float h[DS];
    size_t sbase = (((size_t)b * DI + d) * NCH + c) * DS;
#pragma unroll
    for (int n = 0; n < DS; n++) h[n] = hpart[sbase + n];
    float Dv = Dp[d];
    int l0 = c * CH;
    for (int t = 0; t < CH; t++) {
        size_t row = (size_t)b * L + l0 + t;
        float dtv = dt[row * DI + d];
        float uv = uc[row * DI + d];
        const float* xr = xdbl + row * XDW;
        float du = dtv * uv;
        float yv = 0.f;
#pragma unroll
        for (int n = 0; n < DS; n++) {
            float dA = expf(dtv * Av[n]);
            h[n] = dA * h[n] + du * xr[DTR + n];
            yv += h[n] * xr[DTR + DS + n];
        }
        yv += uv * Dv;
        float zv = xz[row * XZW + DI + d];
        yv *= zv / (1.0f + expf(-zv));
        y[row * DI + d] = yv;
    }
}

// ---------------- mean over L, then head -----------------------------------
__global__ void mean_k(const float* __restrict__ hn, float* __restrict__ hmean) {
    int idx = blockIdx.x * blockDim.x + threadIdx.x;
    if (idx >= B * DM) return;
    int d = idx % DM, b = idx / DM;
    float s = 0.f;
    for (int l = 0; l < L; l++) s += hn[(size_t)(b * L + l) * DM + d];
    hmean[idx] = s * (1.0f / L);
}

__global__ void head_k(const float* __restrict__ hmean, const float* __restrict__ hw,
                       const float* __restrict__ hb, float* __restrict__ out) {
    int t = threadIdx.x;
    if (t >= B * NC) return;
    int b = t / NC, c = t % NC;
    float acc = hb[c];
    for (int k = 0; k < DM; k++) acc += hmean[b * DM + k] * hw[c * DM + k];
    out[t] = acc;
}

extern "C" void kernel_launch(void* const* d_in, const int* in_sizes, int n_in,
                              void* d_out, int out_size, void* d_ws, size_t ws_size,
                              hipStream_t stream) {
    const float* x      = (const float*)d_in[0];
    const float* inp_w  = (const float*)d_in[1];
    const float* inp_b  = (const float*)d_in[2];
    const float* norm_g = (const float*)d_in[3];
    const float* norm_b = (const float*)d_in[4];
    const float* in_w   = (const float*)d_in[5];
    const float* conv_w = (const float*)d_in[6];
    const float* conv_b = (const float*)d_in[7];
    const float* xp_w   = (const float*)d_in[8];
    const float* dt_w   = (const float*)d_in[9];
    const float* dt_b   = (const float*)d_in[10];
    const float* A_log  = (const float*)d_in[11];
    const float* Dp     = (const float*)d_in[12];
    const float* out_w  = (const float*)d_in[13];
    const float* fnorm_g = (const float*)d_in[14];
    const float* fnorm_b = (const float*)d_in[15];
    const float* head_w = (const float*)d_in[16];
    const float* head_b = (const float*)d_in[17];
    float* out = (float*)d_out;

    float* ws = (float*)d_ws;
    float* h     = ws;
    float* hn    = h + (size_t)M * DM;
    float* xz    = hn + (size_t)M * DM;
    float* uc    = xz + (size_t)M * XZW;
    float* xdbl  = uc + (size_t)M * DI;
    float* dtb   = xdbl + (size_t)M * XDW;
    float* yb    = dtb + (size_t)M * DI;
    float* hpart = yb + (size_t)M * DI;
    float* aprod = hpart + (size_t)B * DI * NCH * DS;
    float* hmean = aprod + (size_t)B * DI * NCH * DS;

    // embed
    embed_k<<<(M * DM + 255) / 256, 256, 0, stream>>>(x, inp_w, inp_b, h);

    for (int i = 0; i < NL; i++) {
        const float* inw_i = in_w + (size_t)i * XZW * DM;
        const float* cw_i  = conv_w + (size_t)i * DI * DC;
        const float* cb_i  = conv_b + (size_t)i * DI;
        const float* xpw_i = xp_w + (size_t)i * XDW * DI;
        const float* dtw_i = dt_w + (size_t)i * DI * DTR;
        const float* dtb_i = dt_b + (size_t)i * DI;
        const float* Al_i  = A_log + (size_t)i * DI * DS;
        const float* Dp_i  = Dp + (size_t)i * DI;
        const float* ow_i  = out_w + (size_t)i * DM * DI;

        // hn = LN(h)
        layernorm_k<<<M, 256, 0, stream>>>(h, norm_g + i * DM, norm_b + i * DM, hn);
        // xz = hn @ in_w^T   (M x 2048, K=512)
        gemm_mfma<128, 128, 0><<<dim3(XZW / 128, M / 128), 256, 0, stream>>>(
            hn, DM, inw_i, DM, nullptr, xz, XZW, XZW, DM);
        // uc = silu(conv(u))
        conv_silu_k<<<(M * DI + 255) / 256, 256, 0, stream>>>(xz, cw_i, cb_i, uc);
        // xdbl = uc @ xp_w^T  (M x 48, K=1024), N padded to 64
        gemm_mfma<64, 64, 0><<<dim3(1, M / 64), 256, 0, stream>>>(
            uc, DI, xpw_i, DI, nullptr, xdbl, XDW, XDW, DI);
        // dt = softplus(xdbl[:, :32] @ dt_w^T + dt_b)  (M x 1024, K=32)
        gemm_mfma<128, 128, 2><<<dim3(DI / 128, M / 128), 256, 0, stream>>>(
            xdbl, XDW, dtw_i, DTR, dtb_i, dtb, DI, DI, DTR);
        // selective scan (chunked), fused gate + u*D
        scan_part_k<<<(B * NCH * DI) / 256, 256, 0, stream>>>(dtb, uc, xdbl, Al_i, hpart, aprod);
        scan_combine_k<<<(B * DI + 255) / 256, 256, 0, stream>>>(hpart, aprod);
        scan_emit_k<<<(B * NCH * DI) / 256, 256, 0, stream>>>(dtb, uc, xdbl, xz, Al_i, Dp_i, hpart, yb);
        // h += y @ out_w^T  (M x 512, K=1024)
        gemm_mfma<128, 128, 1><<<dim3(DM / 128, M / 128), 256, 0, stream>>>(
            yb, DI, ow_i, DI, nullptr, h, DM, DM, DI);
    }

    // final LN -> mean over L -> head
    layernorm_k<<<M, 256, 0, stream>>>(h, fnorm_g, fnorm_b, hn);
    mean_k<<<(B * DM + 255) / 256, 256, 0, stream>>>(hn, hmean);
    head_k<<<1, 256, 0, stream>>>(hmean, head_w, head_b, out);
}

// Round 3
// 631.399 us; speedup vs baseline: 2.5732x; 1.5858x over previous
//
#include <hip/hip_runtime.h>
#include <hip/hip_bf16.h>
#include <cstddef>
#include <type_traits>

// Problem constants
constexpr int NL = 2, DM = 512, DI = 1024, DS = 8, DC = 4, DTR = 32, NC = 50;
constexpr int B = 4, L = 2048;
constexpr int M = B * L;          // 8192 rows
constexpr int XZW = 2 * DI;       // 2048
constexpr int XDW = DTR + 2 * DS; // 48
constexpr int NCH = 64, CH = L / NCH; // chunked scan: 64 chunks of 32
constexpr int XSK = 8;            // split-K for x_proj

typedef __bf16 bf16_t;
typedef bf16_t bf16x8 __attribute__((ext_vector_type(8)));
typedef float f32x4 __attribute__((ext_vector_type(4)));

// ---------------- embed: h[b,l,d] = x[b,0,l]*inp_w[d,0] + inp_b[d] ----------
__global__ void embed_k(const float* __restrict__ x, const float* __restrict__ iw,
                        const float* __restrict__ ib, float* __restrict__ h) {
    int idx = blockIdx.x * blockDim.x + threadIdx.x;   // over M*DM/4
    if (idx >= M * DM / 4) return;
    int d4 = idx % (DM / 4);
    int m = idx / (DM / 4);
    float4 w = reinterpret_cast<const float4*>(iw)[d4];
    float4 bb = reinterpret_cast<const float4*>(ib)[d4];
    float xv = x[m];
    float4 r;
    r.x = xv * w.x + bb.x; r.y = xv * w.y + bb.y;
    r.z = xv * w.z + bb.z; r.w = xv * w.w + bb.w;
    reinterpret_cast<float4*>(h)[idx] = r;
}

// ---------------- layernorm over last dim (DM=512), bf16 output -------------
__global__ __launch_bounds__(256) void layernorm_k(const float* __restrict__ in,
                                                   const float* __restrict__ g,
                                                   const float* __restrict__ b,
                                                   bf16_t* __restrict__ out) {
    int row = blockIdx.x;
    const float* x = in + (size_t)row * DM;
    int t = threadIdx.x;
    float v0 = x[t], v1 = x[t + 256];
    float s = v0 + v1, sq = v0 * v0 + v1 * v1;
    for (int o = 32; o > 0; o >>= 1) {
        s += __shfl_down(s, o);
        sq += __shfl_down(sq, o);
    }
    __shared__ float sums[8];
    if ((t & 63) == 0) { sums[t >> 6] = s; sums[4 + (t >> 6)] = sq; }
    __syncthreads();
    float tot = sums[0] + sums[1] + sums[2] + sums[3];
    float totq = sums[4] + sums[5] + sums[6] + sums[7];
    float mu = tot * (1.0f / DM);
    float var = totq * (1.0f / DM) - mu * mu;
    float rs = rsqrtf(var + 1e-5f);
    out[(size_t)row * DM + t]       = (bf16_t)((v0 - mu) * rs * g[t] + b[t]);
    out[(size_t)row * DM + t + 256] = (bf16_t)((v1 - mu) * rs * g[t + 256] + b[t + 256]);
}

// ---------------- bf16 MFMA GEMM: C[m,n] (+)= sum_k A[m,k]*W[n,k] ----------
// TA: float (converted) or bf16 (direct). W fp32 always. TC: float or bf16.
// EPI: 0 = store, 1 = accumulate (C += acc, fp32), 2 = softplus(acc + bias[n])
// SK: split-K factor via blockIdx.z. 256 threads = 4 waves 2x2, BK = 32.
template <int BM, int BN, int EPI, typename TA, typename TC, int SK>
__global__ __launch_bounds__(256) void gemm_mfma(const TA* __restrict__ A, int lda,
                                                 const float* __restrict__ W, int ldw,
                                                 const float* __restrict__ bias,
                                                 TC* __restrict__ C, int ldc,
                                                 int Nr, int K) {
    constexpr int WM = BM / 2, WN = BN / 2;
    constexpr int FM = WM / 16, FN = WN / 16;
    constexpr int ACH = BM * 32 / (256 * 8);
    constexpr int WCH = BN * 32 / (256 * 8);
    __shared__ bf16_t As[BM * 32];
    __shared__ bf16_t Ws[BN * 32];

    int t = threadIdx.x;
    int m0 = blockIdx.y * BM, n0 = blockIdx.x * BN;
    int Ktot = K;
    if constexpr (SK > 1) {
        int s = blockIdx.z;
        Ktot = K / SK;
        A += (size_t)s * Ktot;
        W += (size_t)s * Ktot;
        C += (size_t)s * (size_t)(gridDim.y * BM) * ldc;
    }
    int wave = t >> 6, lane = t & 63;
    int wr = wave >> 1, wc = wave & 1;
    int lr = lane & 15, lk = lane >> 4;

    f32x4 acc[FM][FN];
#pragma unroll
    for (int i = 0; i < FM; i++)
#pragma unroll
        for (int j = 0; j < FN; j++)
#pragma unroll
            for (int q = 0; q < 4; q++) acc[i][j][q] = 0.0f;

    for (int k0 = 0; k0 < Ktot; k0 += 32) {
        __syncthreads();
#pragma unroll
        for (int c = 0; c < ACH; ++c) {
            int e = t + c * 256;
            int r = e >> 2;
            int g = e & 3;
            bf16x8 v;
            if constexpr (std::is_same_v<TA, float>) {
                const float* src = A + (size_t)(m0 + r) * lda + k0 + g * 8;
                float4 f0 = *reinterpret_cast<const float4*>(src);
                float4 f1 = *reinterpret_cast<const float4*>(src + 4);
                v[0] = (bf16_t)f0.x; v[1] = (bf16_t)f0.y; v[2] = (bf16_t)f0.z; v[3] = (bf16_t)f0.w;
                v[4] = (bf16_t)f1.x; v[5] = (bf16_t)f1.y; v[6] = (bf16_t)f1.z; v[7] = (bf16_t)f1.w;
            } else {
                v = *reinterpret_cast<const bf16x8*>(A + (size_t)(m0 + r) * lda + k0 + g * 8);
            }
            int slot = g ^ ((r >> 1) & 3);
            *reinterpret_cast<bf16x8*>(&As[r * 32 + slot * 8]) = v;
        }
#pragma unroll
        for (int c = 0; c < WCH; ++c) {
            int e = t + c * 256;
            int r = e >> 2;
            int g = e & 3;
            bf16x8 v;
#pragma unroll
            for (int q = 0; q < 8; q++) v[q] = (bf16_t)0.0f;
            if (n0 + r < Nr) {
                const float* src = W + (size_t)(n0 + r) * ldw + k0 + g * 8;
                float4 f0 = *reinterpret_cast<const float4*>(src);
                float4 f1 = *reinterpret_cast<const float4*>(src + 4);
                v[0] = (bf16_t)f0.x; v[1] = (bf16_t)f0.y; v[2] = (bf16_t)f0.z; v[3] = (bf16_t)f0.w;
                v[4] = (bf16_t)f1.x; v[5] = (bf16_t)f1.y; v[6] = (bf16_t)f1.z; v[7] = (bf16_t)f1.w;
            }
            int slot = g ^ ((r >> 1) & 3);
            *reinterpret_cast<bf16x8*>(&Ws[r * 32 + slot * 8]) = v;
        }
        __syncthreads();

        bf16x8 af[FM], bfr[FN];
#pragma unroll
        for (int mi = 0; mi < FM; mi++) {
            int r = wr * WM + mi * 16 + lr;
            int slot = lk ^ ((r >> 1) & 3);
            af[mi] = *reinterpret_cast<const bf16x8*>(&As[r * 32 + slot * 8]);
        }
#pragma unroll
        for (int ni = 0; ni < FN; ni++) {
            int r = wc * WN + ni * 16 + lr;
            int slot = lk ^ ((r >> 1) & 3);
            bfr[ni] = *reinterpret_cast<const bf16x8*>(&Ws[r * 32 + slot * 8]);
        }
#pragma unroll
        for (int mi = 0; mi < FM; mi++)
#pragma unroll
            for (int ni = 0; ni < FN; ni++)
                acc[mi][ni] = __builtin_amdgcn_mfma_f32_16x16x32_bf16(af[mi], bfr[ni], acc[mi][ni], 0, 0, 0);
    }

    // epilogue: C/D layout col=lane&15, row=(lane>>4)*4+reg
#pragma unroll
    for (int mi = 0; mi < FM; mi++) {
#pragma unroll
        for (int ni = 0; ni < FN; ni++) {
            int col = n0 + wc * WN + ni * 16 + lr;
            if (col >= Nr) continue;
#pragma unroll
            for (int i = 0; i < 4; i++) {
                int row = m0 + wr * WM + mi * 16 + lk * 4 + i;
                size_t idx = (size_t)row * ldc + col;
                float v = acc[mi][ni][i];
                if constexpr (EPI == 0) {
                    C[idx] = (TC)v;
                } else if constexpr (EPI == 1) {
                    C[idx] += v;
                } else {
                    float s = v + bias[col];
                    C[idx] = (TC)((s > 20.0f) ? s : __logf(1.0f + __expf(s)));
                }
            }
        }
    }
}

// ---------------- x_proj split-K reduce ------------------------------------
__global__ void xproj_reduce_k(const float* __restrict__ part, float* __restrict__ xdbl) {
    int idx = blockIdx.x * blockDim.x + threadIdx.x;
    if (idx >= M * XDW) return;
    int m = idx / XDW, j = idx % XDW;
    float s = 0.f;
#pragma unroll
    for (int sp = 0; sp < XSK; sp++) s += part[((size_t)sp * M + m) * 64 + j];
    xdbl[idx] = s;
}

// ---------------- causal depthwise conv (DC=4) + SiLU -----------------------
__global__ void conv_silu_k(const bf16_t* __restrict__ xz, const float* __restrict__ cw,
                            const float* __restrict__ cb, bf16_t* __restrict__ uc) {
    int idx = blockIdx.x * blockDim.x + threadIdx.x;
    if (idx >= M * DI) return;
    int d = idx % DI;
    int m = idx / DI;
    int b = m / L, l = m % L;
    float acc = cb[d];
#pragma unroll
    for (int k = 0; k < DC; k++) {
        int ls = l + k - (DC - 1);
        if (ls >= 0) acc += (float)xz[(size_t)(b * L + ls) * XZW + d] * cw[d * DC + k];
    }
    uc[idx] = (bf16_t)(acc / (1.0f + __expf(-acc)));
}

// ---------------- selective scan, 3-phase chunked ---------------------------
__global__ __launch_bounds__(256) void scan_part_k(const bf16_t* __restrict__ dt,
                                                   const bf16_t* __restrict__ uc,
                                                   const float* __restrict__ xdbl,
                                                   const float* __restrict__ A_log,
                                                   float* __restrict__ hpart,
                                                   float* __restrict__ aprod) {
    int gid = blockIdx.x * 256 + threadIdx.x;
    if (gid >= B * NCH * DI) return;
    int d = gid % DI;
    int c = (gid / DI) % NCH;
    int b = gid / (DI * NCH);
    float Av[DS];
#pragma unroll
    for (int n = 0; n < DS; n++) Av[n] = -__expf(A_log[d * DS + n]);
    float h[DS] = {};
    float ap[DS];
#pragma unroll
    for (int n = 0; n < DS; n++) ap[n] = 1.0f;
    int l0 = c * CH;
    for (int t = 0; t < CH; t++) {
        size_t row = (size_t)b * L + l0 + t;
        float dtv = (float)dt[row * DI + d];
        float uv = (float)uc[row * DI + d];
        const float* xr = xdbl + row * XDW;
        float du = dtv * uv;
#pragma unroll
        for (int n = 0; n < DS; n++) {
            float dA = __expf(dtv * Av[n]);
            h[n] = dA * h[n] + du * xr[DTR + n];
            ap[n] *= dA;
        }
    }
    size_t base = (((size_t)b * DI + d) * NCH + c) * DS;
#pragma unroll
    for (int n = 0; n < DS; n++) {
        hpart[base + n] = h[n];
        aprod[base + n] = ap[n];
    }
}

// per (b,d,n) sequential combine over chunks; hpart[c] := state BEFORE chunk c
__global__ void scan_combine_k(float* __restrict__ hpart, const float* __restrict__ aprod) {
    int gid = blockIdx.x * blockDim.x + threadIdx.x;
    if (gid >= B * DI * DS) return;
    int n = gid & (DS - 1);
    int d = (gid >> 3) & (DI - 1);
    int b = gid >> 13;
    size_t base = ((size_t)(b * DI + d) * NCH) * DS + n;
    float hrun = 0.f;
    for (int c = 0; c < NCH; c++) {
        size_t idx = base + (size_t)c * DS;
        float ap = aprod[idx];
        float hp = hpart[idx];
        hpart[idx] = hrun;
        hrun = ap * hrun + hp;
    }
}

__global__ __launch_bounds__(256) void scan_emit_k(const bf16_t* __restrict__ dt,
                                                   const bf16_t* __restrict__ uc,
                                                   const float* __restrict__ xdbl,
                                                   const bf16_t* __restrict__ xz,
                                                   const float* __restrict__ A_log,
                                                   const float* __restrict__ Dp,
                                                   const float* __restrict__ hpart,
                                                   bf16_t* __restrict__ y) {
    int gid = blockIdx.x * 256 + threadIdx.x;
    if (gid >= B * NCH * DI) return;
    int d = gid % DI;
    int c = (gid / DI) % NCH;
    int b = gid / (DI * NCH);
    float Av[DS];
#pragma unroll
    for (int n = 0; n < DS; n++) Av[n] = -__expf(A_log[d * DS + n]);
    float h[DS];
    size_t sbase = (((size_t)b * DI + d) * NCH + c) * DS;
#pragma unroll
    for (int n = 0; n < DS; n++) h[n] = hpart[sbase + n];
    float Dv = Dp[d];
    int l0 = c * CH;
    for (int t = 0; t < CH; t++) {
        size_t row = (size_t)b * L + l0 + t;
        float dtv = (float)dt[row * DI + d];
        float uv = (float)uc[row * DI + d];
        const float* xr = xdbl + row * XDW;
        float du = dtv * uv;
        float yv = 0.f;
#pragma unroll
        for (int n = 0; n < DS; n++) {
            float dA = __expf(dtv * Av[n]);
            h[n] = dA * h[n] + du * xr[DTR + n];
            yv += h[n] * xr[DTR + DS + n];
        }
        yv += uv * Dv;
        float zv = (float)xz[row * XZW + DI + d];
        yv *= zv / (1.0f + __expf(-zv));
        y[row * DI + d] = (bf16_t)yv;
    }
}

// ---------------- mean over L (2-stage), then head --------------------------
__global__ __launch_bounds__(256) void mean_part_k(const bf16_t* __restrict__ hn,
                                                   float* __restrict__ partial) {
    int c = blockIdx.x;   // 32 chunks of 64 rows
    int b = blockIdx.y;
    int t = threadIdx.x;
    float s0 = 0.f, s1 = 0.f;
    for (int l = 0; l < L / 32; l++) {
        const bf16_t* row = hn + (size_t)(b * L + c * (L / 32) + l) * DM;
        s0 += (float)row[t];
        s1 += (float)row[t + 256];
    }
    partial[(size_t)(b * 32 + c) * DM + t] = s0;
    partial[(size_t)(b * 32 + c) * DM + t + 256] = s1;
}

__global__ void mean_fin_k(const float* __restrict__ partial, float* __restrict__ hmean) {
    int idx = blockIdx.x * blockDim.x + threadIdx.x;
    if (idx >= B * DM) return;
    int b = idx / DM, d = idx % DM;
    float s = 0.f;
#pragma unroll
    for (int c = 0; c < 32; c++) s += partial[(size_t)(b * 32 + c) * DM + d];
    hmean[idx] = s * (1.0f / L);
}

__global__ void head_k(const float* __restrict__ hmean, const float* __restrict__ hw,
                       const float* __restrict__ hb, float* __restrict__ out) {
    int t = threadIdx.x;
    if (t >= B * NC) return;
    int b = t / NC, c = t % NC;
    float acc = hb[c];
    for (int k = 0; k < DM; k++) acc += hmean[b * DM + k] * hw[c * DM + k];
    out[t] = acc;
}

extern "C" void kernel_launch(void* const* d_in, const int* in_sizes, int n_in,
                              void* d_out, int out_size, void* d_ws, size_t ws_size,
                              hipStream_t stream) {
    const float* x      = (const float*)d_in[0];
    const float* inp_w  = (const float*)d_in[1];
    const float* inp_b  = (const float*)d_in[2];
    const float* norm_g = (const float*)d_in[3];
    const float* norm_b = (const float*)d_in[4];
    const float* in_w   = (const float*)d_in[5];
    const float* conv_w = (const float*)d_in[6];
    const float* conv_b = (const float*)d_in[7];
    const float* xp_w   = (const float*)d_in[8];
    const float* dt_w   = (const float*)d_in[9];
    const float* dt_b   = (const float*)d_in[10];
    const float* A_log  = (const float*)d_in[11];
    const float* Dp     = (const float*)d_in[12];
    const float* out_w  = (const float*)d_in[13];
    const float* fnorm_g = (const float*)d_in[14];
    const float* fnorm_b = (const float*)d_in[15];
    const float* head_w = (const float*)d_in[16];
    const float* head_b = (const float*)d_in[17];
    float* out = (float*)d_out;

    char* p = (char*)d_ws;
    float*  h     = (float*)p;  p += (size_t)M * DM * 4;
    bf16_t* hn    = (bf16_t*)p; p += (size_t)M * DM * 2;
    bf16_t* xz    = (bf16_t*)p; p += (size_t)M * XZW * 2;
    bf16_t* uc    = (bf16_t*)p; p += (size_t)M * DI * 2;
    float*  xdbl  = (float*)p;  p += (size_t)M * XDW * 4;
    bf16_t* dtb   = (bf16_t*)p; p += (size_t)M * DI * 2;
    bf16_t* yb    = (bf16_t*)p; p += (size_t)M * DI * 2;
    float*  hpart = (float*)p;  p += (size_t)B * DI * NCH * DS * 4;
    float*  aprod = (float*)p;  p += (size_t)B * DI * NCH * DS * 4;
    float*  xpart = (float*)p;  p += (size_t)XSK * M * 64 * 4;
    float*  partial = (float*)p; p += (size_t)B * 32 * DM * 4;
    float*  hmean = (float*)p;  p += (size_t)B * DM * 4;

    // embed (vectorized)
    embed_k<<<(M * DM / 4 + 255) / 256, 256, 0, stream>>>(x, inp_w, inp_b, h);

    for (int i = 0; i < NL; i++) {
        const float* inw_i = in_w + (size_t)i * XZW * DM;
        const float* cw_i  = conv_w + (size_t)i * DI * DC;
        const float* cb_i  = conv_b + (size_t)i * DI;
        const float* xpw_i = xp_w + (size_t)i * XDW * DI;
        const float* dtw_i = dt_w + (size_t)i * DI * DTR;
        const float* dtb_i = dt_b + (size_t)i * DI;
        const float* Al_i  = A_log + (size_t)i * DI * DS;
        const float* Dp_i  = Dp + (size_t)i * DI;
        const float* ow_i  = out_w + (size_t)i * DM * DI;

        // hn = LN(h) -> bf16
        layernorm_k<<<M, 256, 0, stream>>>(h, norm_g + i * DM, norm_b + i * DM, hn);
        // xz = hn @ in_w^T   (M x 2048, K=512)
        gemm_mfma<128, 128, 0, bf16_t, bf16_t, 1><<<dim3(XZW / 128, M / 128), 256, 0, stream>>>(
            hn, DM, inw_i, DM, nullptr, xz, XZW, XZW, DM);
        // uc = silu(conv(u))
        conv_silu_k<<<(M * DI + 255) / 256, 256, 0, stream>>>(xz, cw_i, cb_i, uc);
        // xdbl = uc @ xp_w^T  (M x 48, K=1024) split-K=8 -> partials, then reduce
        gemm_mfma<64, 64, 0, bf16_t, float, XSK><<<dim3(1, M / 64, XSK), 256, 0, stream>>>(
            uc, DI, xpw_i, DI, nullptr, xpart, 64, XDW, DI);
        xproj_reduce_k<<<(M * XDW + 255) / 256, 256, 0, stream>>>(xpart, xdbl);
        // dt = softplus(xdbl[:, :32] @ dt_w^T + dt_b)  (M x 1024, K=32)
        gemm_mfma<128, 128, 2, float, bf16_t, 1><<<dim3(DI / 128, M / 128), 256, 0, stream>>>(
            xdbl, XDW, dtw_i, DTR, dtb_i, dtb, DI, DI, DTR);
        // selective scan (chunked), fused gate + u*D
        scan_part_k<<<(B * NCH * DI) / 256, 256, 0, stream>>>(dtb, uc, xdbl, Al_i, hpart, aprod);
        scan_combine_k<<<(B * DI * DS + 255) / 256, 256, 0, stream>>>(hpart, aprod);
        scan_emit_k<<<(B * NCH * DI) / 256, 256, 0, stream>>>(dtb, uc, xdbl, xz, Al_i, Dp_i, hpart, yb);
        // h += y @ out_w^T  (M x 512, K=1024)
        gemm_mfma<128, 128, 1, bf16_t, float, 1><<<dim3(DM / 128, M / 128), 256, 0, stream>>>(
            yb, DI, ow_i, DI, nullptr, h, DM, DM, DI);
    }

    // final LN -> mean over L (2-stage) -> head
    layernorm_k<<<M, 256, 0, stream>>>(h, fnorm_g, fnorm_b, hn);
    mean_part_k<<<dim3(32, B), 256, 0, stream>>>(hn, partial);
    mean_fin_k<<<(B * DM + 255) / 256, 256, 0, stream>>>(partial, hmean);
    head_k<<<1, 256, 0, stream>>>(hmean, head_w, head_b, out);
}

// Round 6
// 539.269 us; speedup vs baseline: 3.0128x; 1.1708x over previous
//
#include <hip/hip_runtime.h>
#include <hip/hip_bf16.h>
#include <cstddef>

// Problem constants
constexpr int NL = 2, DM = 512, DI = 1024, DS = 8, DC = 4, DTR = 32, NC = 50;
constexpr int B = 4, L = 2048;
constexpr int M = B * L;          // 8192 rows
constexpr int XZW = 2 * DI;       // 2048
constexpr int XDW = DTR + 2 * DS; // 48
constexpr int NCH = 64, CH = L / NCH; // chunked scan: 64 chunks of 32
constexpr int XSK = 8;            // split-K for x_proj

typedef __bf16 bf16_t;
typedef bf16_t bf16x8 __attribute__((ext_vector_type(8)));
typedef bf16_t bf16x4 __attribute__((ext_vector_type(4)));
typedef float f32x4 __attribute__((ext_vector_type(4)));

// ---------------- embed ------------------------------------------------------
__global__ void embed_k(const float* __restrict__ x, const float* __restrict__ iw,
                        const float* __restrict__ ib, float* __restrict__ h) {
    int idx = blockIdx.x * blockDim.x + threadIdx.x;   // over M*DM/4
    if (idx >= M * DM / 4) return;
    int d4 = idx % (DM / 4);
    int m = idx / (DM / 4);
    float4 w = reinterpret_cast<const float4*>(iw)[d4];
    float4 bb = reinterpret_cast<const float4*>(ib)[d4];
    float xv = x[m];
    float4 r;
    r.x = xv * w.x + bb.x; r.y = xv * w.y + bb.y;
    r.z = xv * w.z + bb.z; r.w = xv * w.w + bb.w;
    reinterpret_cast<float4*>(h)[idx] = r;
}

// ---------------- weight fp32 -> bf16 (all 4 arrays, both layers, fused) ----
constexpr int WN1 = NL * XZW * DM / 4;
constexpr int WN2 = NL * XDW * DI / 4;
constexpr int WN3 = NL * DI * DTR / 4;
constexpr int WN4 = NL * DM * DI / 4;
constexpr int WNT = WN1 + WN2 + WN3 + WN4;
__global__ void cvt_ws_k(const float* __restrict__ s1, const float* __restrict__ s2,
                         const float* __restrict__ s3, const float* __restrict__ s4,
                         bf16_t* __restrict__ d1, bf16_t* __restrict__ d2,
                         bf16_t* __restrict__ d3, bf16_t* __restrict__ d4) {
    int i4 = blockIdx.x * 256 + threadIdx.x;
    const float* s; bf16_t* d; int off;
    if (i4 < WN1) { s = s1; d = d1; off = i4; }
    else if (i4 < WN1 + WN2) { s = s2; d = d2; off = i4 - WN1; }
    else if (i4 < WN1 + WN2 + WN3) { s = s3; d = d3; off = i4 - WN1 - WN2; }
    else if (i4 < WNT) { s = s4; d = d4; off = i4 - WN1 - WN2 - WN3; }
    else return;
    float4 f = reinterpret_cast<const float4*>(s)[off];
    bf16x4 v;
    v[0] = (bf16_t)f.x; v[1] = (bf16_t)f.y; v[2] = (bf16_t)f.z; v[3] = (bf16_t)f.w;
    *reinterpret_cast<bf16x4*>(d + (size_t)off * 4) = v;
}

// ---------------- layernorm over last dim (DM=512), bf16 output -------------
__global__ __launch_bounds__(256) void layernorm_k(const float* __restrict__ in,
                                                   const float* __restrict__ g,
                                                   const float* __restrict__ b,
                                                   bf16_t* __restrict__ out) {
    int row = blockIdx.x;
    const float* x = in + (size_t)row * DM;
    int t = threadIdx.x;
    float v0 = x[t], v1 = x[t + 256];
    float s = v0 + v1, sq = v0 * v0 + v1 * v1;
    for (int o = 32; o > 0; o >>= 1) {
        s += __shfl_down(s, o);
        sq += __shfl_down(sq, o);
    }
    __shared__ float sums[8];
    if ((t & 63) == 0) { sums[t >> 6] = s; sums[4 + (t >> 6)] = sq; }
    __syncthreads();
    float tot = sums[0] + sums[1] + sums[2] + sums[3];
    float totq = sums[4] + sums[5] + sums[6] + sums[7];
    float mu = tot * (1.0f / DM);
    float var = totq * (1.0f / DM) - mu * mu;
    float rs = rsqrtf(var + 1e-5f);
    out[(size_t)row * DM + t]       = (bf16_t)((v0 - mu) * rs * g[t] + b[t]);
    out[(size_t)row * DM + t + 256] = (bf16_t)((v1 - mu) * rs * g[t + 256] + b[t + 256]);
}

// ---------------- bf16 MFMA GEMM: C[m,n] (+)= sum_k A[m,k]*W[n,k] ----------
// A, W bf16. EPI: 0 = store, 1 = accumulate (fp32), 2 = softplus(acc+bias[n])
// Double-buffered LDS + register prefetch, ONE barrier per K-step.
// 256 threads = 4 waves 2x2. BK = 32. SK: split-K via blockIdx.z.
template <int BM, int BN, int EPI, typename TC, int SK>
__global__ __launch_bounds__(256) void gemm_mfma(const bf16_t* __restrict__ A, int lda,
                                                 const bf16_t* __restrict__ W, int ldw,
                                                 const float* __restrict__ bias,
                                                 TC* __restrict__ C, int ldc,
                                                 int Nr, int K) {
    constexpr int WM = BM / 2, WN = BN / 2;
    constexpr int FM = WM / 16, FN = WN / 16;
    constexpr int ACH = BM * 32 / (256 * 8);
    constexpr int WCH = BN * 32 / (256 * 8);
    __shared__ bf16_t As[2][BM * 32];
    __shared__ bf16_t Ws[2][BN * 32];

    int tid = threadIdx.x;
    int m0 = blockIdx.y * BM, n0 = blockIdx.x * BN;
    int Ktot = K;
    if constexpr (SK > 1) {
        int s = blockIdx.z;
        Ktot = K / SK;
        A += (size_t)s * Ktot;
        W += (size_t)s * Ktot;
        C += (size_t)s * (size_t)(gridDim.y * BM) * ldc;
    }
    int wave = tid >> 6, lane = tid & 63;
    int wr = wave >> 1, wc = wave & 1;
    int lr = lane & 15, lk = lane >> 4;

    auto load_tile = [&](int k0, bf16x8* ra, bf16x8* rw) {
#pragma unroll
        for (int c = 0; c < ACH; ++c) {
            int e = tid + c * 256;
            int r = e >> 2, g = e & 3;
            ra[c] = *reinterpret_cast<const bf16x8*>(A + (size_t)(m0 + r) * lda + k0 + g * 8);
        }
#pragma unroll
        for (int c = 0; c < WCH; ++c) {
            int e = tid + c * 256;
            int r = e >> 2, g = e & 3;
            bf16x8 z;
#pragma unroll
            for (int q = 0; q < 8; q++) z[q] = (bf16_t)0.0f;
            rw[c] = (n0 + r < Nr)
                ? *reinterpret_cast<const bf16x8*>(W + (size_t)(n0 + r) * ldw + k0 + g * 8)
                : z;
        }
    };
    auto store_tile = [&](const bf16x8* ra, const bf16x8* rw, int buf) {
#pragma unroll
        for (int c = 0; c < ACH; ++c) {
            int e = tid + c * 256;
            int r = e >> 2, g = e & 3;
            int slot = g ^ ((r >> 1) & 3);
            *reinterpret_cast<bf16x8*>(&As[buf][r * 32 + slot * 8]) = ra[c];
        }
#pragma unroll
        for (int c = 0; c < WCH; ++c) {
            int e = tid + c * 256;
            int r = e >> 2, g = e & 3;
            int slot = g ^ ((r >> 1) & 3);
            *reinterpret_cast<bf16x8*>(&Ws[buf][r * 32 + slot * 8]) = rw[c];
        }
    };

    f32x4 acc[FM][FN];
#pragma unroll
    for (int i = 0; i < FM; i++)
#pragma unroll
        for (int j = 0; j < FN; j++)
#pragma unroll
            for (int q = 0; q < 4; q++) acc[i][j][q] = 0.0f;

    bf16x8 pa[ACH], pw[WCH];
    load_tile(0, pa, pw);
    store_tile(pa, pw, 0);
    __syncthreads();

    int nt = Ktot / 32;
    int cur = 0;
    for (int t = 0; t < nt; ++t) {
        bool pf = (t + 1 < nt);
        if (pf) load_tile((t + 1) * 32, pa, pw);

        bf16x8 af[FM], bfr[FN];
#pragma unroll
        for (int mi = 0; mi < FM; mi++) {
            int r = wr * WM + mi * 16 + lr;
            int slot = lk ^ ((r >> 1) & 3);
            af[mi] = *reinterpret_cast<const bf16x8*>(&As[cur][r * 32 + slot * 8]);
        }
#pragma unroll
        for (int ni = 0; ni < FN; ni++) {
            int r = wc * WN + ni * 16 + lr;
            int slot = lk ^ ((r >> 1) & 3);
            bfr[ni] = *reinterpret_cast<const bf16x8*>(&Ws[cur][r * 32 + slot * 8]);
        }
#pragma unroll
        for (int mi = 0; mi < FM; mi++)
#pragma unroll
            for (int ni = 0; ni < FN; ni++)
                acc[mi][ni] = __builtin_amdgcn_mfma_f32_16x16x32_bf16(af[mi], bfr[ni], acc[mi][ni], 0, 0, 0);

        if (pf) {
            store_tile(pa, pw, cur ^ 1);
            __syncthreads();
            cur ^= 1;
        }
    }

    // epilogue: C/D layout col=lane&15, row=(lane>>4)*4+reg
#pragma unroll
    for (int mi = 0; mi < FM; mi++) {
#pragma unroll
        for (int ni = 0; ni < FN; ni++) {
            int col = n0 + wc * WN + ni * 16 + lr;
            if (col >= Nr) continue;
#pragma unroll
            for (int i = 0; i < 4; i++) {
                int row = m0 + wr * WM + mi * 16 + lk * 4 + i;
                size_t idx = (size_t)row * ldc + col;
                float v = acc[mi][ni][i];
                if constexpr (EPI == 0) {
                    C[idx] = (TC)v;
                } else if constexpr (EPI == 1) {
                    C[idx] += v;
                } else {
                    float s = v + bias[col];
                    C[idx] = (TC)((s > 20.0f) ? s : __logf(1.0f + __expf(s)));
                }
            }
        }
    }
}

// ---------------- x_proj split-K reduce (also emits bf16 dt-input copy) -----
__global__ void xproj_reduce_k(const float* __restrict__ part, float* __restrict__ xdbl,
                               bf16_t* __restrict__ xdt) {
    int idx = blockIdx.x * blockDim.x + threadIdx.x;
    if (idx >= M * XDW) return;
    int m = idx / XDW, j = idx % XDW;
    float s = 0.f;
#pragma unroll
    for (int sp = 0; sp < XSK; sp++) s += part[((size_t)sp * M + m) * 64 + j];
    xdbl[idx] = s;
    if (j < DTR) xdt[(size_t)m * DTR + j] = (bf16_t)s;
}

// ---------------- causal depthwise conv (DC=4) + SiLU -----------------------
__global__ void conv_silu_k(const bf16_t* __restrict__ xz, const float* __restrict__ cw,
                            const float* __restrict__ cb, bf16_t* __restrict__ uc) {
    int idx = blockIdx.x * blockDim.x + threadIdx.x;
    if (idx >= M * DI) return;
    int d = idx % DI;
    int m = idx / DI;
    int b = m / L, l = m % L;
    float acc = cb[d];
#pragma unroll
    for (int k = 0; k < DC; k++) {
        int ls = l + k - (DC - 1);
        if (ls >= 0) acc += (float)xz[(size_t)(b * L + ls) * XZW + d] * cw[d * DC + k];
    }
    uc[idx] = (bf16_t)(acc / (1.0f + __expf(-acc)));
}

// ---------------- selective scan, 3-phase chunked ---------------------------
__global__ __launch_bounds__(256) void scan_part_k(const bf16_t* __restrict__ dt,
                                                   const bf16_t* __restrict__ uc,
                                                   const float* __restrict__ xdbl,
                                                   const float* __restrict__ A_log,
                                                   float* __restrict__ hpart,
                                                   float* __restrict__ aprod) {
    int gid = blockIdx.x * 256 + threadIdx.x;
    if (gid >= B * NCH * DI) return;
    int d = gid % DI;
    int c = (gid / DI) % NCH;
    int b = gid / (DI * NCH);
    float Av[DS];
#pragma unroll
    for (int n = 0; n < DS; n++) Av[n] = -__expf(A_log[d * DS + n]);
    float h[DS] = {};
    float ap[DS];
#pragma unroll
    for (int n = 0; n < DS; n++) ap[n] = 1.0f;
    int l0 = c * CH;
    for (int t = 0; t < CH; t++) {
        size_t row = (size_t)b * L + l0 + t;
        float dtv = (float)dt[row * DI + d];
        float uv = (float)uc[row * DI + d];
        const float* xr = xdbl + row * XDW;
        float du = dtv * uv;
#pragma unroll
        for (int n = 0; n < DS; n++) {
            float dA = __expf(dtv * Av[n]);
            h[n] = dA * h[n] + du * xr[DTR + n];
            ap[n] *= dA;
        }
    }
    size_t base = (((size_t)b * DI + d) * NCH + c) * DS;
#pragma unroll
    for (int n = 0; n < DS; n++) {
        hpart[base + n] = h[n];
        aprod[base + n] = ap[n];
    }
}

// per (b,d,n) sequential combine over chunks; hpart[c] := state BEFORE chunk c
__global__ void scan_combine_k(float* __restrict__ hpart, const float* __restrict__ aprod) {
    int gid = blockIdx.x * blockDim.x + threadIdx.x;
    if (gid >= B * DI * DS) return;
    int n = gid & (DS - 1);
    int d = (gid >> 3) & (DI - 1);
    int b = gid >> 13;
    size_t base = ((size_t)(b * DI + d) * NCH) * DS + n;
    float hrun = 0.f;
    for (int c = 0; c < NCH; c++) {
        size_t idx = base + (size_t)c * DS;
        float ap = aprod[idx];
        float hp = hpart[idx];
        hpart[idx] = hrun;
        hrun = ap * hrun + hp;
    }
}

__global__ __launch_bounds__(256) void scan_emit_k(const bf16_t* __restrict__ dt,
                                                   const bf16_t* __restrict__ uc,
                                                   const float* __restrict__ xdbl,
                                                   const bf16_t* __restrict__ xz,
                                                   const float* __restrict__ A_log,
                                                   const float* __restrict__ Dp,
                                                   const float* __restrict__ hpart,
                                                   bf16_t* __restrict__ y) {
    int gid = blockIdx.x * 256 + threadIdx.x;
    if (gid >= B * NCH * DI) return;
    int d = gid % DI;
    int c = (gid / DI) % NCH;
    int b = gid / (DI * NCH);
    float Av[DS];
#pragma unroll
    for (int n = 0; n < DS; n++) Av[n] = -__expf(A_log[d * DS + n]);
    float h[DS];
    size_t sbase = (((size_t)b * DI + d) * NCH + c) * DS;
#pragma unroll
    for (int n = 0; n < DS; n++) h[n] = hpart[sbase + n];
    float Dv = Dp[d];
    int l0 = c * CH;
    for (int t = 0; t < CH; t++) {
        size_t row = (size_t)b * L + l0 + t;
        float dtv = (float)dt[row * DI + d];
        float uv = (float)uc[row * DI + d];
        const float* xr = xdbl + row * XDW;
        float du = dtv * uv;
        float yv = 0.f;
#pragma unroll
        for (int n = 0; n < DS; n++) {
            float dA = __expf(dtv * Av[n]);
            h[n] = dA * h[n] + du * xr[DTR + n];
            yv += h[n] * xr[DTR + DS + n];
        }
        yv += uv * Dv;
        float zv = (float)xz[row * XZW + DI + d];
        yv *= zv / (1.0f + __expf(-zv));
        y[row * DI + d] = (bf16_t)yv;
    }
}

// ---------------- mean over L (2-stage), then head --------------------------
__global__ __launch_bounds__(256) void mean_part_k(const bf16_t* __restrict__ hn,
                                                   float* __restrict__ partial) {
    int c = blockIdx.x;   // 32 chunks of 64 rows
    int b = blockIdx.y;
    int t = threadIdx.x;
    float s0 = 0.f, s1 = 0.f;
    for (int l = 0; l < L / 32; l++) {
        const bf16_t* row = hn + (size_t)(b * L + c * (L / 32) + l) * DM;
        s0 += (float)row[t];
        s1 += (float)row[t + 256];
    }
    partial[(size_t)(b * 32 + c) * DM + t] = s0;
    partial[(size_t)(b * 32 + c) * DM + t + 256] = s1;
}

__global__ void mean_fin_k(const float* __restrict__ partial, float* __restrict__ hmean) {
    int idx = blockIdx.x * blockDim.x + threadIdx.x;
    if (idx >= B * DM) return;
    int b = idx / DM, d = idx % DM;
    float s = 0.f;
#pragma unroll
    for (int c = 0; c < 32; c++) s += partial[(size_t)(b * 32 + c) * DM + d];
    hmean[idx] = s * (1.0f / L);
}

__global__ void head_k(const float* __restrict__ hmean, const float* __restrict__ hw,
                       const float* __restrict__ hb, float* __restrict__ out) {
    int t = threadIdx.x;
    if (t >= B * NC) return;
    int b = t / NC, c = t % NC;
    float acc = hb[c];
    for (int k = 0; k < DM; k++) acc += hmean[b * DM + k] * hw[c * DM + k];
    out[t] = acc;
}

extern "C" void kernel_launch(void* const* d_in, const int* in_sizes, int n_in,
                              void* d_out, int out_size, void* d_ws, size_t ws_size,
                              hipStream_t stream) {
    const float* x      = (const float*)d_in[0];
    const float* inp_w  = (const float*)d_in[1];
    const float* inp_b  = (const float*)d_in[2];
    const float* norm_g = (const float*)d_in[3];
    const float* norm_b = (const float*)d_in[4];
    const float* in_w   = (const float*)d_in[5];
    const float* conv_w = (const float*)d_in[6];
    const float* conv_b = (const float*)d_in[7];
    const float* xp_w   = (const float*)d_in[8];
    const float* dt_w   = (const float*)d_in[9];
    const float* dt_b   = (const float*)d_in[10];
    const float* A_log  = (const float*)d_in[11];
    const float* Dp     = (const float*)d_in[12];
    const float* out_w  = (const float*)d_in[13];
    const float* fnorm_g = (const float*)d_in[14];
    const float* fnorm_b = (const float*)d_in[15];
    const float* head_w = (const float*)d_in[16];
    const float* head_b = (const float*)d_in[17];
    float* out = (float*)d_out;

    char* p = (char*)d_ws;
    float*  h     = (float*)p;  p += (size_t)M * DM * 4;
    bf16_t* hn    = (bf16_t*)p; p += (size_t)M * DM * 2;
    bf16_t* xz    = (bf16_t*)p; p += (size_t)M * XZW * 2;
    bf16_t* uc    = (bf16_t*)p; p += (size_t)M * DI * 2;
    float*  xdbl  = (float*)p;  p += (size_t)M * XDW * 4;
    bf16_t* xdt   = (bf16_t*)p; p += (size_t)M * DTR * 2;
    bf16_t* dtb   = (bf16_t*)p; p += (size_t)M * DI * 2;
    bf16_t* yb    = (bf16_t*)p; p += (size_t)M * DI * 2;
    float*  hpart = (float*)p;  p += (size_t)B * DI * NCH * DS * 4;
    float*  aprod = (float*)p;  p += (size_t)B * DI * NCH * DS * 4;
    float*  xpart = (float*)p;  p += (size_t)XSK * M * 64 * 4;
    float*  partial = (float*)p; p += (size_t)B * 32 * DM * 4;
    float*  hmean = (float*)p;  p += (size_t)B * DM * 4;
    bf16_t* wb_in = (bf16_t*)p; p += (size_t)NL * XZW * DM * 2;
    bf16_t* wb_xp = (bf16_t*)p; p += (size_t)NL * XDW * DI * 2;
    bf16_t* wb_dt = (bf16_t*)p; p += (size_t)NL * DI * DTR * 2;
    bf16_t* wb_out = (bf16_t*)p; p += (size_t)NL * DM * DI * 2;

    // weights -> bf16 (once per call)
    cvt_ws_k<<<(WNT + 255) / 256, 256, 0, stream>>>(in_w, xp_w, dt_w, out_w,
                                                    wb_in, wb_xp, wb_dt, wb_out);
    // embed (vectorized)
    embed_k<<<(M * DM / 4 + 255) / 256, 256, 0, stream>>>(x, inp_w, inp_b, h);

    for (int i = 0; i < NL; i++) {
        const bf16_t* inw_i = wb_in + (size_t)i * XZW * DM;
        const float* cw_i  = conv_w + (size_t)i * DI * DC;
        const float* cb_i  = conv_b + (size_t)i * DI;
        const bf16_t* xpw_i = wb_xp + (size_t)i * XDW * DI;
        const bf16_t* dtw_i = wb_dt + (size_t)i * DI * DTR;
        const float* dtb_i = dt_b + (size_t)i * DI;
        const float* Al_i  = A_log + (size_t)i * DI * DS;
        const float* Dp_i  = Dp + (size_t)i * DI;
        const bf16_t* ow_i  = wb_out + (size_t)i * DM * DI;

        // hn = LN(h) -> bf16
        layernorm_k<<<M, 256, 0, stream>>>(h, norm_g + i * DM, norm_b + i * DM, hn);
        // xz = hn @ in_w^T   (M x 2048, K=512), 128x64 tiles -> 2048 blocks
        gemm_mfma<128, 64, 0, bf16_t, 1><<<dim3(XZW / 64, M / 128), 256, 0, stream>>>(
            hn, DM, inw_i, DM, nullptr, xz, XZW, XZW, DM);
        // uc = silu(conv(u))
        conv_silu_k<<<(M * DI + 255) / 256, 256, 0, stream>>>(xz, cw_i, cb_i, uc);
        // xdbl = uc @ xp_w^T  (M x 48, K=1024) split-K=8 -> partials, then reduce
        gemm_mfma<64, 64, 0, float, XSK><<<dim3(1, M / 64, XSK), 256, 0, stream>>>(
            uc, DI, xpw_i, DI, nullptr, xpart, 64, XDW, DI);
        xproj_reduce_k<<<(M * XDW + 255) / 256, 256, 0, stream>>>(xpart, xdbl, xdt);
        // dt = softplus(xdt @ dt_w^T + dt_b)  (M x 1024, K=32)
        gemm_mfma<64, 64, 2, bf16_t, 1><<<dim3(DI / 64, M / 64), 256, 0, stream>>>(
            xdt, DTR, dtw_i, DTR, dtb_i, dtb, DI, DI, DTR);
        // selective scan (chunked), fused gate + u*D
        scan_part_k<<<(B * NCH * DI) / 256, 256, 0, stream>>>(dtb, uc, xdbl, Al_i, hpart, aprod);
        scan_combine_k<<<(B * DI * DS + 255) / 256, 256, 0, stream>>>(hpart, aprod);
        scan_emit_k<<<(B * NCH * DI) / 256, 256, 0, stream>>>(dtb, uc, xdbl, xz, Al_i, Dp_i, hpart, yb);
        // h += y @ out_w^T  (M x 512, K=1024), 64x64 tiles -> 1024 blocks
        gemm_mfma<64, 64, 1, float, 1><<<dim3(DM / 64, M / 64), 256, 0, stream>>>(
            yb, DI, ow_i, DI, nullptr, h, DM, DM, DI);
    }

    // final LN -> mean over L (2-stage) -> head
    layernorm_k<<<M, 256, 0, stream>>>(h, fnorm_g, fnorm_b, hn);
    mean_part_k<<<dim3(32, B), 256, 0, stream>>>(hn, partial);
    mean_fin_k<<<(B * DM + 255) / 256, 256, 0, stream>>>(partial, hmean);
    head_k<<<1, 256, 0, stream>>>(hmean, head_w, head_b, out);
}

// Round 9
// 497.717 us; speedup vs baseline: 3.2644x; 1.0835x over previous
//
#include <hip/hip_runtime.h>
#include <hip/hip_bf16.h>
#include <cstddef>

// Problem constants
constexpr int NL = 2, DM = 512, DI = 1024, DS = 8, DC = 4, DTR = 32, NC = 50;
constexpr int B = 4, L = 2048;
constexpr int M = B * L;          // 8192 rows
constexpr int XZW = 2 * DI;       // 2048
constexpr int XDW = DTR + 2 * DS; // 48
constexpr int NCH = 64, CH = L / NCH; // chunked scan: 64 chunks of 32
constexpr int XSK = 8;            // split-K for x_proj

typedef __bf16 bf16_t;
typedef bf16_t bf16x8 __attribute__((ext_vector_type(8)));
typedef bf16_t bf16x4 __attribute__((ext_vector_type(4)));
typedef float f32x4 __attribute__((ext_vector_type(4)));

// ---------------- embed ------------------------------------------------------
__global__ void embed_k(const float* __restrict__ x, const float* __restrict__ iw,
                        const float* __restrict__ ib, float* __restrict__ h) {
    int idx = blockIdx.x * blockDim.x + threadIdx.x;   // over M*DM/4
    if (idx >= M * DM / 4) return;
    int d4 = idx % (DM / 4);
    int m = idx / (DM / 4);
    float4 w = reinterpret_cast<const float4*>(iw)[d4];
    float4 bb = reinterpret_cast<const float4*>(ib)[d4];
    float xv = x[m];
    float4 r;
    r.x = xv * w.x + bb.x; r.y = xv * w.y + bb.y;
    r.z = xv * w.z + bb.z; r.w = xv * w.w + bb.w;
    reinterpret_cast<float4*>(h)[idx] = r;
}

// ---------------- weight fp32 -> bf16 (all 4 arrays, both layers, fused) ----
constexpr int WN1 = NL * XZW * DM / 4;
constexpr int WN2 = NL * XDW * DI / 4;
constexpr int WN3 = NL * DI * DTR / 4;
constexpr int WN4 = NL * DM * DI / 4;
constexpr int WNT = WN1 + WN2 + WN3 + WN4;
__global__ void cvt_ws_k(const float* __restrict__ s1, const float* __restrict__ s2,
                         const float* __restrict__ s3, const float* __restrict__ s4,
                         bf16_t* __restrict__ d1, bf16_t* __restrict__ d2,
                         bf16_t* __restrict__ d3, bf16_t* __restrict__ d4) {
    int i4 = blockIdx.x * 256 + threadIdx.x;
    const float* s; bf16_t* d; int off;
    if (i4 < WN1) { s = s1; d = d1; off = i4; }
    else if (i4 < WN1 + WN2) { s = s2; d = d2; off = i4 - WN1; }
    else if (i4 < WN1 + WN2 + WN3) { s = s3; d = d3; off = i4 - WN1 - WN2; }
    else if (i4 < WNT) { s = s4; d = d4; off = i4 - WN1 - WN2 - WN3; }
    else return;
    float4 f = reinterpret_cast<const float4*>(s)[off];
    bf16x4 v;
    v[0] = (bf16_t)f.x; v[1] = (bf16_t)f.y; v[2] = (bf16_t)f.z; v[3] = (bf16_t)f.w;
    *reinterpret_cast<bf16x4*>(d + (size_t)off * 4) = v;
}

// ---------------- layernorm over last dim (DM=512), bf16 output -------------
__global__ __launch_bounds__(256) void layernorm_k(const float* __restrict__ in,
                                                   const float* __restrict__ g,
                                                   const float* __restrict__ b,
                                                   bf16_t* __restrict__ out) {
    int row = blockIdx.x;
    const float* x = in + (size_t)row * DM;
    int t = threadIdx.x;
    float v0 = x[t], v1 = x[t + 256];
    float s = v0 + v1, sq = v0 * v0 + v1 * v1;
    for (int o = 32; o > 0; o >>= 1) {
        s += __shfl_down(s, o);
        sq += __shfl_down(sq, o);
    }
    __shared__ float sums[8];
    if ((t & 63) == 0) { sums[t >> 6] = s; sums[4 + (t >> 6)] = sq; }
    __syncthreads();
    float tot = sums[0] + sums[1] + sums[2] + sums[3];
    float totq = sums[4] + sums[5] + sums[6] + sums[7];
    float mu = tot * (1.0f / DM);
    float var = totq * (1.0f / DM) - mu * mu;
    float rs = rsqrtf(var + 1e-5f);
    out[(size_t)row * DM + t]       = (bf16_t)((v0 - mu) * rs * g[t] + b[t]);
    out[(size_t)row * DM + t + 256] = (bf16_t)((v1 - mu) * rs * g[t + 256] + b[t + 256]);
}

// ---------------- bf16 MFMA GEMM: C[m,n] (+)= sum_k A[m,k]*W[n,k] ----------
// A, W bf16. EPI: 0 = store, 1 = accumulate (fp32), 2 = softplus(acc+bias[n])
// Double-buffered LDS + register prefetch, ONE barrier per K-step.
// 256 threads = 4 waves 2x2. BK = 32. SK: split-K via blockIdx.z.
template <int BM, int BN, int EPI, typename TC, int SK>
__global__ __launch_bounds__(256) void gemm_mfma(const bf16_t* __restrict__ A, int lda,
                                                 const bf16_t* __restrict__ W, int ldw,
                                                 const float* __restrict__ bias,
                                                 TC* __restrict__ C, int ldc,
                                                 int Nr, int K) {
    constexpr int WM = BM / 2, WN = BN / 2;
    constexpr int FM = WM / 16, FN = WN / 16;
    constexpr int ACH = BM * 32 / (256 * 8);
    constexpr int WCH = BN * 32 / (256 * 8);
    __shared__ bf16_t As[2][BM * 32];
    __shared__ bf16_t Ws[2][BN * 32];

    int tid = threadIdx.x;
    int m0 = blockIdx.y * BM, n0 = blockIdx.x * BN;
    int Ktot = K;
    if constexpr (SK > 1) {
        int s = blockIdx.z;
        Ktot = K / SK;
        A += (size_t)s * Ktot;
        W += (size_t)s * Ktot;
        C += (size_t)s * (size_t)(gridDim.y * BM) * ldc;
    }
    int wave = tid >> 6, lane = tid & 63;
    int wr = wave >> 1, wc = wave & 1;
    int lr = lane & 15, lk = lane >> 4;

    auto load_tile = [&](int k0, bf16x8* ra, bf16x8* rw) {
#pragma unroll
        for (int c = 0; c < ACH; ++c) {
            int e = tid + c * 256;
            int r = e >> 2, g = e & 3;
            ra[c] = *reinterpret_cast<const bf16x8*>(A + (size_t)(m0 + r) * lda + k0 + g * 8);
        }
#pragma unroll
        for (int c = 0; c < WCH; ++c) {
            int e = tid + c * 256;
            int r = e >> 2, g = e & 3;
            bf16x8 z;
#pragma unroll
            for (int q = 0; q < 8; q++) z[q] = (bf16_t)0.0f;
            rw[c] = (n0 + r < Nr)
                ? *reinterpret_cast<const bf16x8*>(W + (size_t)(n0 + r) * ldw + k0 + g * 8)
                : z;
        }
    };
    auto store_tile = [&](const bf16x8* ra, const bf16x8* rw, int buf) {
#pragma unroll
        for (int c = 0; c < ACH; ++c) {
            int e = tid + c * 256;
            int r = e >> 2, g = e & 3;
            int slot = g ^ ((r >> 1) & 3);
            *reinterpret_cast<bf16x8*>(&As[buf][r * 32 + slot * 8]) = ra[c];
        }
#pragma unroll
        for (int c = 0; c < WCH; ++c) {
            int e = tid + c * 256;
            int r = e >> 2, g = e & 3;
            int slot = g ^ ((r >> 1) & 3);
            *reinterpret_cast<bf16x8*>(&Ws[buf][r * 32 + slot * 8]) = rw[c];
        }
    };

    f32x4 acc[FM][FN];
#pragma unroll
    for (int i = 0; i < FM; i++)
#pragma unroll
        for (int j = 0; j < FN; j++)
#pragma unroll
            for (int q = 0; q < 4; q++) acc[i][j][q] = 0.0f;

    bf16x8 pa[ACH], pw[WCH];
    load_tile(0, pa, pw);
    store_tile(pa, pw, 0);
    __syncthreads();

    int nt = Ktot / 32;
    int cur = 0;
    for (int t = 0; t < nt; ++t) {
        bool pf = (t + 1 < nt);
        if (pf) load_tile((t + 1) * 32, pa, pw);

        bf16x8 af[FM], bfr[FN];
#pragma unroll
        for (int mi = 0; mi < FM; mi++) {
            int r = wr * WM + mi * 16 + lr;
            int slot = lk ^ ((r >> 1) & 3);
            af[mi] = *reinterpret_cast<const bf16x8*>(&As[cur][r * 32 + slot * 8]);
        }
#pragma unroll
        for (int ni = 0; ni < FN; ni++) {
            int r = wc * WN + ni * 16 + lr;
            int slot = lk ^ ((r >> 1) & 3);
            bfr[ni] = *reinterpret_cast<const bf16x8*>(&Ws[cur][r * 32 + slot * 8]);
        }
#pragma unroll
        for (int mi = 0; mi < FM; mi++)
#pragma unroll
            for (int ni = 0; ni < FN; ni++)
                acc[mi][ni] = __builtin_amdgcn_mfma_f32_16x16x32_bf16(af[mi], bfr[ni], acc[mi][ni], 0, 0, 0);

        if (pf) {
            store_tile(pa, pw, cur ^ 1);
            __syncthreads();
            cur ^= 1;
        }
    }

    // epilogue: C/D layout col=lane&15, row=(lane>>4)*4+reg
#pragma unroll
    for (int mi = 0; mi < FM; mi++) {
#pragma unroll
        for (int ni = 0; ni < FN; ni++) {
            int col = n0 + wc * WN + ni * 16 + lr;
            if (col >= Nr) continue;
#pragma unroll
            for (int i = 0; i < 4; i++) {
                int row = m0 + wr * WM + mi * 16 + lk * 4 + i;
                size_t idx = (size_t)row * ldc + col;
                float v = acc[mi][ni][i];
                if constexpr (EPI == 0) {
                    C[idx] = (TC)v;
                } else if constexpr (EPI == 1) {
                    C[idx] += v;
                } else {
                    float s = v + bias[col];
                    C[idx] = (TC)((s > 20.0f) ? s : __logf(1.0f + __expf(s)));
                }
            }
        }
    }
}

// ---------------- x_proj split-K reduce (also emits bf16 dt-input copy) -----
__global__ void xproj_reduce_k(const float* __restrict__ part, float* __restrict__ xdbl,
                               bf16_t* __restrict__ xdt) {
    int idx = blockIdx.x * blockDim.x + threadIdx.x;
    if (idx >= M * XDW) return;
    int m = idx / XDW, j = idx % XDW;
    float s = 0.f;
#pragma unroll
    for (int sp = 0; sp < XSK; sp++) s += part[((size_t)sp * M + m) * 64 + j];
    xdbl[idx] = s;
    if (j < DTR) xdt[(size_t)m * DTR + j] = (bf16_t)s;
}

// ---------------- causal depthwise conv (DC=4) + SiLU, 8 channels/thread ----
__global__ __launch_bounds__(256) void conv_silu_k(const bf16_t* __restrict__ xz,
                                                   const float* __restrict__ cw,
                                                   const float* __restrict__ cb,
                                                   bf16_t* __restrict__ uc) {
    int idx = blockIdx.x * blockDim.x + threadIdx.x;   // over M*DI/8
    if (idx >= M * DI / 8) return;
    int d8 = idx % (DI / 8);
    int m = idx / (DI / 8);
    int b = m / L, l = m % L;
    int d0 = d8 * 8;

    float acc[8];
    {
        float4 c0 = *reinterpret_cast<const float4*>(cb + d0);
        float4 c1 = *reinterpret_cast<const float4*>(cb + d0 + 4);
        acc[0] = c0.x; acc[1] = c0.y; acc[2] = c0.z; acc[3] = c0.w;
        acc[4] = c1.x; acc[5] = c1.y; acc[6] = c1.z; acc[7] = c1.w;
    }
    float4 w[8];
#pragma unroll
    for (int j = 0; j < 8; j++)
        w[j] = *reinterpret_cast<const float4*>(cw + (size_t)(d0 + j) * DC);

#pragma unroll
    for (int k = 0; k < DC; k++) {
        int ls = l + k - (DC - 1);
        if (ls < 0) continue;
        bf16x8 v = *reinterpret_cast<const bf16x8*>(xz + (size_t)(b * L + ls) * XZW + d0);
        float wk[8] = {w[0].x, w[1].x, w[2].x, w[3].x, w[4].x, w[5].x, w[6].x, w[7].x};
        if (k == 1) { wk[0]=w[0].y; wk[1]=w[1].y; wk[2]=w[2].y; wk[3]=w[3].y; wk[4]=w[4].y; wk[5]=w[5].y; wk[6]=w[6].y; wk[7]=w[7].y; }
        if (k == 2) { wk[0]=w[0].z; wk[1]=w[1].z; wk[2]=w[2].z; wk[3]=w[3].z; wk[4]=w[4].z; wk[5]=w[5].z; wk[6]=w[6].z; wk[7]=w[7].z; }
        if (k == 3) { wk[0]=w[0].w; wk[1]=w[1].w; wk[2]=w[2].w; wk[3]=w[3].w; wk[4]=w[4].w; wk[5]=w[5].w; wk[6]=w[6].w; wk[7]=w[7].w; }
#pragma unroll
        for (int j = 0; j < 8; j++) acc[j] += (float)v[j] * wk[j];
    }
    bf16x8 o;
#pragma unroll
    for (int j = 0; j < 8; j++) {
        float a = acc[j];
        o[j] = (bf16_t)(a / (1.0f + __expf(-a)));
    }
    *reinterpret_cast<bf16x8*>(uc + (size_t)m * DI + d0) = o;
}

// ---------------- selective scan, 3-phase chunked ---------------------------
// hpart/aprod layout: [b][c][d][n] (coalesced float4 along d)
__global__ __launch_bounds__(256) void scan_part_k(const bf16_t* __restrict__ dt,
                                                   const bf16_t* __restrict__ uc,
                                                   const float* __restrict__ xdbl,
                                                   const float* __restrict__ A_log,
                                                   float* __restrict__ hpart,
                                                   float* __restrict__ aprod) {
    int gid = blockIdx.x * 256 + threadIdx.x;
    if (gid >= B * NCH * DI) return;
    int d = gid % DI;
    int c = (gid / DI) % NCH;
    int b = gid / (DI * NCH);
    float Av[DS];
    {
        float4 a0 = *reinterpret_cast<const float4*>(A_log + d * DS);
        float4 a1 = *reinterpret_cast<const float4*>(A_log + d * DS + 4);
        Av[0] = -__expf(a0.x); Av[1] = -__expf(a0.y); Av[2] = -__expf(a0.z); Av[3] = -__expf(a0.w);
        Av[4] = -__expf(a1.x); Av[5] = -__expf(a1.y); Av[6] = -__expf(a1.z); Av[7] = -__expf(a1.w);
    }
    float h[DS] = {};
    float ap[DS];
#pragma unroll
    for (int n = 0; n < DS; n++) ap[n] = 1.0f;
    int l0 = c * CH;
    for (int t = 0; t < CH; t++) {
        size_t row = (size_t)b * L + l0 + t;
        float dtv = (float)dt[row * DI + d];
        float uv = (float)uc[row * DI + d];
        const float4* xr4 = reinterpret_cast<const float4*>(xdbl + row * XDW + DTR);
        float4 b0 = xr4[0], b1 = xr4[1];
        float Bv[DS] = {b0.x, b0.y, b0.z, b0.w, b1.x, b1.y, b1.z, b1.w};
        float du = dtv * uv;
#pragma unroll
        for (int n = 0; n < DS; n++) {
            float dA = __expf(dtv * Av[n]);
            h[n] = dA * h[n] + du * Bv[n];
            ap[n] *= dA;
        }
    }
    size_t base = (((size_t)(b * NCH + c) * DI) + d) * DS;
    f32x4* hp4 = reinterpret_cast<f32x4*>(hpart + base);
    f32x4* ap4 = reinterpret_cast<f32x4*>(aprod + base);
    f32x4 v0, v1, w0, w1;
#pragma unroll
    for (int n = 0; n < 4; n++) { v0[n] = h[n]; v1[n] = h[n + 4]; w0[n] = ap[n]; w1[n] = ap[n + 4]; }
    hp4[0] = v0; hp4[1] = v1;
    ap4[0] = w0; ap4[1] = w1;
}

// per (b,d,n) sequential combine over chunks; hpart[c] := state BEFORE chunk c
__global__ void scan_combine_k(float* __restrict__ hpart, const float* __restrict__ aprod) {
    int gid = blockIdx.x * blockDim.x + threadIdx.x;
    if (gid >= B * DI * DS) return;
    int dn = gid & (DI * DS - 1);      // (d,n) combined: consecutive lanes coalesced
    int b = gid >> 13;
    float hrun = 0.f;
    for (int c = 0; c < NCH; c++) {
        size_t idx = ((size_t)(b * NCH + c) * DI * DS) + dn;
        float ap = aprod[idx];
        float hp = hpart[idx];
        hpart[idx] = hrun;
        hrun = ap * hrun + hp;
    }
}

__global__ __launch_bounds__(256) void scan_emit_k(const bf16_t* __restrict__ dt,
                                                   const bf16_t* __restrict__ uc,
                                                   const float* __restrict__ xdbl,
                                                   const bf16_t* __restrict__ xz,
                                                   const float* __restrict__ A_log,
                                                   const float* __restrict__ Dp,
                                                   const float* __restrict__ hpart,
                                                   bf16_t* __restrict__ y) {
    int gid = blockIdx.x * 256 + threadIdx.x;
    if (gid >= B * NCH * DI) return;
    int d = gid % DI;
    int c = (gid / DI) % NCH;
    int b = gid / (DI * NCH);
    float Av[DS];
    {
        float4 a0 = *reinterpret_cast<const float4*>(A_log + d * DS);
        float4 a1 = *reinterpret_cast<const float4*>(A_log + d * DS + 4);
        Av[0] = -__expf(a0.x); Av[1] = -__expf(a0.y); Av[2] = -__expf(a0.z); Av[3] = -__expf(a0.w);
        Av[4] = -__expf(a1.x); Av[5] = -__expf(a1.y); Av[6] = -__expf(a1.z); Av[7] = -__expf(a1.w);
    }
    float h[DS];
    {
        size_t base = (((size_t)(b * NCH + c) * DI) + d) * DS;
        const f32x4* hp4 = reinterpret_cast<const f32x4*>(hpart + base);
        f32x4 v0 = hp4[0], v1 = hp4[1];
#pragma unroll
        for (int n = 0; n < 4; n++) { h[n] = v0[n]; h[n + 4] = v1[n]; }
    }
    float Dv = Dp[d];
    int l0 = c * CH;
    for (int t = 0; t < CH; t++) {
        size_t row = (size_t)b * L + l0 + t;
        float dtv = (float)dt[row * DI + d];
        float uv = (float)uc[row * DI + d];
        const float4* xr4 = reinterpret_cast<const float4*>(xdbl + row * XDW + DTR);
        float4 b0 = xr4[0], b1 = xr4[1], c0 = xr4[2], c1 = xr4[3];
        float Bv[DS] = {b0.x, b0.y, b0.z, b0.w, b1.x, b1.y, b1.z, b1.w};
        float Cv[DS] = {c0.x, c0.y, c0.z, c0.w, c1.x, c1.y, c1.z, c1.w};
        float du = dtv * uv;
        float yv = 0.f;
#pragma unroll
        for (int n = 0; n < DS; n++) {
            float dA = __expf(dtv * Av[n]);
            h[n] = dA * h[n] + du * Bv[n];
            yv += h[n] * Cv[n];
        }
        yv += uv * Dv;
        float zv = (float)xz[row * XZW + DI + d];
        yv *= zv / (1.0f + __expf(-zv));
        y[row * DI + d] = (bf16_t)yv;
    }
}

// ---------------- mean over L (2-stage), then head --------------------------
// partial layout: [b][c*4+rsub][DM]
__global__ __launch_bounds__(256) void mean_part_k(const bf16_t* __restrict__ hn,
                                                   float* __restrict__ partial) {
    int c = blockIdx.x;   // 32 chunks of 64 rows
    int b = blockIdx.y;
    int t = threadIdx.x;
    int d0 = (t & 63) * 8;
    int rsub = t >> 6;    // 4 row subsets
    float s[8] = {};
    for (int l = rsub; l < 64; l += 4) {
        bf16x8 v = *reinterpret_cast<const bf16x8*>(hn + (size_t)(b * L + c * 64 + l) * DM + d0);
#pragma unroll
        for (int j = 0; j < 8; j++) s[j] += (float)v[j];
    }
    float* dst = partial + ((size_t)(b * 32 + c) * 4 + rsub) * DM + d0;
    f32x4 o0, o1;
#pragma unroll
    for (int j = 0; j < 4; j++) { o0[j] = s[j]; o1[j] = s[j + 4]; }
    reinterpret_cast<f32x4*>(dst)[0] = o0;
    reinterpret_cast<f32x4*>(dst)[1] = o1;
}

__global__ void mean_fin_k(const float* __restrict__ partial, float* __restrict__ hmean) {
    int idx = blockIdx.x * blockDim.x + threadIdx.x;
    if (idx >= B * DM) return;
    int b = idx / DM, d = idx % DM;
    float s = 0.f;
    for (int c = 0; c < 128; c++) s += partial[((size_t)b * 128 + c) * DM + d];
    hmean[idx] = s * (1.0f / L);
}

__global__ void head_k(const float* __restrict__ hmean, const float* __restrict__ hw,
                       const float* __restrict__ hb, float* __restrict__ out) {
    int t = threadIdx.x;
    if (t >= B * NC) return;
    int b = t / NC, c = t % NC;
    float acc = hb[c];
    for (int k = 0; k < DM; k++) acc += hmean[b * DM + k] * hw[c * DM + k];
    out[t] = acc;
}

extern "C" void kernel_launch(void* const* d_in, const int* in_sizes, int n_in,
                              void* d_out, int out_size, void* d_ws, size_t ws_size,
                              hipStream_t stream) {
    const float* x      = (const float*)d_in[0];
    const float* inp_w  = (const float*)d_in[1];
    const float* inp_b  = (const float*)d_in[2];
    const float* norm_g = (const float*)d_in[3];
    const float* norm_b = (const float*)d_in[4];
    const float* in_w   = (const float*)d_in[5];
    const float* conv_w = (const float*)d_in[6];
    const float* conv_b = (const float*)d_in[7];
    const float* xp_w   = (const float*)d_in[8];
    const float* dt_w   = (const float*)d_in[9];
    const float* dt_b   = (const float*)d_in[10];
    const float* A_log  = (const float*)d_in[11];
    const float* Dp     = (const float*)d_in[12];
    const float* out_w  = (const float*)d_in[13];
    const float* fnorm_g = (const float*)d_in[14];
    const float* fnorm_b = (const float*)d_in[15];
    const float* head_w = (const float*)d_in[16];
    const float* head_b = (const float*)d_in[17];
    float* out = (float*)d_out;

    char* p = (char*)d_ws;
    float*  h     = (float*)p;  p += (size_t)M * DM * 4;
    bf16_t* hn    = (bf16_t*)p; p += (size_t)M * DM * 2;
    bf16_t* xz    = (bf16_t*)p; p += (size_t)M * XZW * 2;
    bf16_t* uc    = (bf16_t*)p; p += (size_t)M * DI * 2;
    float*  xdbl  = (float*)p;  p += (size_t)M * XDW * 4;
    bf16_t* xdt   = (bf16_t*)p; p += (size_t)M * DTR * 2;
    bf16_t* dtb   = (bf16_t*)p; p += (size_t)M * DI * 2;
    bf16_t* yb    = (bf16_t*)p; p += (size_t)M * DI * 2;
    float*  hpart = (float*)p;  p += (size_t)B * DI * NCH * DS * 4;
    float*  aprod = (float*)p;  p += (size_t)B * DI * NCH * DS * 4;
    float*  xpart = (float*)p;  p += (size_t)XSK * M * 64 * 4;
    float*  partial = (float*)p; p += (size_t)B * 128 * DM * 4;
    float*  hmean = (float*)p;  p += (size_t)B * DM * 4;
    bf16_t* wb_in = (bf16_t*)p; p += (size_t)NL * XZW * DM * 2;
    bf16_t* wb_xp = (bf16_t*)p; p += (size_t)NL * XDW * DI * 2;
    bf16_t* wb_dt = (bf16_t*)p; p += (size_t)NL * DI * DTR * 2;
    bf16_t* wb_out = (bf16_t*)p; p += (size_t)NL * DM * DI * 2;

    // weights -> bf16 (once per call)
    cvt_ws_k<<<(WNT + 255) / 256, 256, 0, stream>>>(in_w, xp_w, dt_w, out_w,
                                                    wb_in, wb_xp, wb_dt, wb_out);
    // embed (vectorized)
    embed_k<<<(M * DM / 4 + 255) / 256, 256, 0, stream>>>(x, inp_w, inp_b, h);

    for (int i = 0; i < NL; i++) {
        const bf16_t* inw_i = wb_in + (size_t)i * XZW * DM;
        const float* cw_i  = conv_w + (size_t)i * DI * DC;
        const float* cb_i  = conv_b + (size_t)i * DI;
        const bf16_t* xpw_i = wb_xp + (size_t)i * XDW * DI;
        const bf16_t* dtw_i = wb_dt + (size_t)i * DI * DTR;
        const float* dtb_i = dt_b + (size_t)i * DI;
        const float* Al_i  = A_log + (size_t)i * DI * DS;
        const float* Dp_i  = Dp + (size_t)i * DI;
        const bf16_t* ow_i  = wb_out + (size_t)i * DM * DI;

        // hn = LN(h) -> bf16
        layernorm_k<<<M, 256, 0, stream>>>(h, norm_g + i * DM, norm_b + i * DM, hn);
        // xz = hn @ in_w^T   (M x 2048, K=512), 128x64 tiles -> 2048 blocks
        gemm_mfma<128, 64, 0, bf16_t, 1><<<dim3(XZW / 64, M / 128), 256, 0, stream>>>(
            hn, DM, inw_i, DM, nullptr, xz, XZW, XZW, DM);
        // uc = silu(conv(u)), 8 ch/thread
        conv_silu_k<<<(M * DI / 8 + 255) / 256, 256, 0, stream>>>(xz, cw_i, cb_i, uc);
        // xdbl = uc @ xp_w^T  (M x 48, K=1024) split-K=8 -> partials, then reduce
        gemm_mfma<64, 64, 0, float, XSK><<<dim3(1, M / 64, XSK), 256, 0, stream>>>(
            uc, DI, xpw_i, DI, nullptr, xpart, 64, XDW, DI);
        xproj_reduce_k<<<(M * XDW + 255) / 256, 256, 0, stream>>>(xpart, xdbl, xdt);
        // dt = softplus(xdt @ dt_w^T + dt_b)  (M x 1024, K=32)
        gemm_mfma<64, 64, 2, bf16_t, 1><<<dim3(DI / 64, M / 64), 256, 0, stream>>>(
            xdt, DTR, dtw_i, DTR, dtb_i, dtb, DI, DI, DTR);
        // selective scan (chunked), fused gate + u*D
        scan_part_k<<<(B * NCH * DI) / 256, 256, 0, stream>>>(dtb, uc, xdbl, Al_i, hpart, aprod);
        scan_combine_k<<<(B * DI * DS + 255) / 256, 256, 0, stream>>>(hpart, aprod);
        scan_emit_k<<<(B * NCH * DI) / 256, 256, 0, stream>>>(dtb, uc, xdbl, xz, Al_i, Dp_i, hpart, yb);
        // h += y @ out_w^T  (M x 512, K=1024), 64x64 tiles -> 1024 blocks
        gemm_mfma<64, 64, 1, float, 1><<<dim3(DM / 64, M / 64), 256, 0, stream>>>(
            yb, DI, ow_i, DI, nullptr, h, DM, DM, DI);
    }

    // final LN -> mean over L (2-stage) -> head
    layernorm_k<<<M, 256, 0, stream>>>(h, fnorm_g, fnorm_b, hn);
    mean_part_k<<<dim3(32, B), 256, 0, stream>>>(hn, partial);
    mean_fin_k<<<(B * DM + 255) / 256, 256, 0, stream>>>(partial, hmean);
    head_k<<<1, 256, 0, stream>>>(hmean, head_w, head_b, out);
}

// Round 10
// 490.850 us; speedup vs baseline: 3.3100x; 1.0140x over previous
//
#include <hip/hip_runtime.h>
#include <hip/hip_bf16.h>
#include <cstddef>

// Problem constants
constexpr int NL = 2, DM = 512, DI = 1024, DS = 8, DC = 4, DTR = 32, NC = 50;
constexpr int B = 4, L = 2048;
constexpr int M = B * L;          // 8192 rows
constexpr int XZW = 2 * DI;       // 2048
constexpr int XDW = DTR + 2 * DS; // 48
constexpr int XPR = 64;           // x_proj weight rows padded to 64
constexpr int NCH = 64, CH = L / NCH; // chunked scan: 64 chunks of 32
constexpr int XSK = 8;            // split-K for x_proj

typedef __bf16 bf16_t;
typedef bf16_t bf16x8 __attribute__((ext_vector_type(8)));
typedef bf16_t bf16x4 __attribute__((ext_vector_type(4)));
typedef float f32x4 __attribute__((ext_vector_type(4)));

// async global->LDS, 16 bytes per lane
__device__ __forceinline__ void gload16(const bf16_t* g, bf16_t* l) {
    __builtin_amdgcn_global_load_lds(
        (const __attribute__((address_space(1))) void*)g,
        (__attribute__((address_space(3))) void*)l, 16, 0, 0);
}

// ---------------- embed + layer-0 LN fused ----------------------------------
__global__ __launch_bounds__(256) void embed_ln_k(const float* __restrict__ x,
                                                  const float* __restrict__ iw,
                                                  const float* __restrict__ ib,
                                                  const float* __restrict__ g,
                                                  const float* __restrict__ bvec,
                                                  float* __restrict__ h,
                                                  bf16_t* __restrict__ out) {
    int row = blockIdx.x;
    int t = threadIdx.x;
    float xv = x[row];
    float v0 = xv * iw[t] + ib[t];
    float v1 = xv * iw[t + 256] + ib[t + 256];
    h[(size_t)row * DM + t] = v0;
    h[(size_t)row * DM + t + 256] = v1;
    float s = v0 + v1, sq = v0 * v0 + v1 * v1;
    for (int o = 32; o > 0; o >>= 1) {
        s += __shfl_down(s, o);
        sq += __shfl_down(sq, o);
    }
    __shared__ float sums[8];
    if ((t & 63) == 0) { sums[t >> 6] = s; sums[4 + (t >> 6)] = sq; }
    __syncthreads();
    float tot = sums[0] + sums[1] + sums[2] + sums[3];
    float totq = sums[4] + sums[5] + sums[6] + sums[7];
    float mu = tot * (1.0f / DM);
    float var = totq * (1.0f / DM) - mu * mu;
    float rs = rsqrtf(var + 1e-5f);
    out[(size_t)row * DM + t]       = (bf16_t)((v0 - mu) * rs * g[t] + bvec[t]);
    out[(size_t)row * DM + t + 256] = (bf16_t)((v1 - mu) * rs * g[t + 256] + bvec[t + 256]);
}

// ---------------- weight fp32 -> bf16 (xp padded to 64 rows with zeros) -----
constexpr int WN1 = NL * XZW * DM / 4;
constexpr int WN2p = NL * XPR * DI / 4;
constexpr int WN3 = NL * DI * DTR / 4;
constexpr int WN4 = NL * DM * DI / 4;
constexpr int WNTp = WN1 + WN2p + WN3 + WN4;
__global__ void cvt_ws_k(const float* __restrict__ s1, const float* __restrict__ s2,
                         const float* __restrict__ s3, const float* __restrict__ s4,
                         bf16_t* __restrict__ d1, bf16_t* __restrict__ d2,
                         bf16_t* __restrict__ d3, bf16_t* __restrict__ d4) {
    int i4 = blockIdx.x * 256 + threadIdx.x;
    if (i4 >= WNTp) return;
    if (i4 < WN1) {
        float4 f = reinterpret_cast<const float4*>(s1)[i4];
        bf16x4 v;
        v[0] = (bf16_t)f.x; v[1] = (bf16_t)f.y; v[2] = (bf16_t)f.z; v[3] = (bf16_t)f.w;
        *reinterpret_cast<bf16x4*>(d1 + (size_t)i4 * 4) = v;
    } else if (i4 < WN1 + WN2p) {
        int off = i4 - WN1;
        int layer = off / (XPR * DI / 4);
        int rem = off % (XPR * DI / 4);
        int row = rem / (DI / 4);
        int c4 = rem % (DI / 4);
        bf16x4 v;
        if (row < XDW) {
            float4 f = reinterpret_cast<const float4*>(s2)[((size_t)layer * XDW + row) * (DI / 4) + c4];
            v[0] = (bf16_t)f.x; v[1] = (bf16_t)f.y; v[2] = (bf16_t)f.z; v[3] = (bf16_t)f.w;
        } else {
            v[0] = (bf16_t)0.f; v[1] = (bf16_t)0.f; v[2] = (bf16_t)0.f; v[3] = (bf16_t)0.f;
        }
        *reinterpret_cast<bf16x4*>(d2 + (size_t)off * 4) = v;
    } else if (i4 < WN1 + WN2p + WN3) {
        int off = i4 - WN1 - WN2p;
        float4 f = reinterpret_cast<const float4*>(s3)[off];
        bf16x4 v;
        v[0] = (bf16_t)f.x; v[1] = (bf16_t)f.y; v[2] = (bf16_t)f.z; v[3] = (bf16_t)f.w;
        *reinterpret_cast<bf16x4*>(d3 + (size_t)off * 4) = v;
    } else {
        int off = i4 - WN1 - WN2p - WN3;
        float4 f = reinterpret_cast<const float4*>(s4)[off];
        bf16x4 v;
        v[0] = (bf16_t)f.x; v[1] = (bf16_t)f.y; v[2] = (bf16_t)f.z; v[3] = (bf16_t)f.w;
        *reinterpret_cast<bf16x4*>(d4 + (size_t)off * 4) = v;
    }
}

// ---------------- layernorm over last dim (DM=512), bf16 output -------------
__global__ __launch_bounds__(256) void layernorm_k(const float* __restrict__ in,
                                                   const float* __restrict__ g,
                                                   const float* __restrict__ b,
                                                   bf16_t* __restrict__ out) {
    int row = blockIdx.x;
    const float* x = in + (size_t)row * DM;
    int t = threadIdx.x;
    float v0 = x[t], v1 = x[t + 256];
    float s = v0 + v1, sq = v0 * v0 + v1 * v1;
    for (int o = 32; o > 0; o >>= 1) {
        s += __shfl_down(s, o);
        sq += __shfl_down(sq, o);
    }
    __shared__ float sums[8];
    if ((t & 63) == 0) { sums[t >> 6] = s; sums[4 + (t >> 6)] = sq; }
    __syncthreads();
    float tot = sums[0] + sums[1] + sums[2] + sums[3];
    float totq = sums[4] + sums[5] + sums[6] + sums[7];
    float mu = tot * (1.0f / DM);
    float var = totq * (1.0f / DM) - mu * mu;
    float rs = rsqrtf(var + 1e-5f);
    out[(size_t)row * DM + t]       = (bf16_t)((v0 - mu) * rs * g[t] + b[t]);
    out[(size_t)row * DM + t + 256] = (bf16_t)((v1 - mu) * rs * g[t + 256] + b[t + 256]);
}

// ---------------- bf16 MFMA GEMM: C[m,n] (+)= sum_k A[m,k]*W[n,k] ----------
// global_load_lds staging, pre-swizzled source + linear LDS dest, dbuf,
// one barrier per K-step. 256 threads = 4 waves 2x2. BK = 32.
// EPI: 0 = store, 1 = accumulate (fp32), 2 = softplus(acc+bias[n])
template <int BM, int BN, int EPI, typename TC, int SK>
__global__ __launch_bounds__(256) void gemm_mfma(const bf16_t* __restrict__ A, int lda,
                                                 const bf16_t* __restrict__ W, int ldw,
                                                 const float* __restrict__ bias,
                                                 TC* __restrict__ C, int ldc,
                                                 int Nr, int K) {
    constexpr int WM = BM / 2, WN = BN / 2;
    constexpr int FM = WM / 16, FN = WN / 16;
    __shared__ __align__(16) bf16_t As[2][BM * 32];
    __shared__ __align__(16) bf16_t Ws[2][BN * 32];

    int tid = threadIdx.x;
    int m0 = blockIdx.y * BM, n0 = blockIdx.x * BN;
    int Ktot = K;
    if constexpr (SK > 1) {
        int s = blockIdx.z;
        Ktot = K / SK;
        A += (size_t)s * Ktot;
        W += (size_t)s * Ktot;
        C += (size_t)s * (size_t)(gridDim.y * BM) * ldc;
    }
    int wave = tid >> 6, lane = tid & 63;
    int wr = wave >> 1, wc = wave & 1;
    int lr = lane & 15, lk = lane >> 4;

    auto stage = [&](int k0, int buf) {
#pragma unroll
        for (int c = 0; c < BM / 64; ++c) {
            int e = tid + c * 256;
            int r = e >> 2, slot = e & 3;
            int g = slot ^ ((r >> 1) & 3);
            gload16(A + (size_t)(m0 + r) * lda + k0 + g * 8, &As[buf][e * 8]);
        }
#pragma unroll
        for (int c = 0; c < BN / 64; ++c) {
            int e = tid + c * 256;
            int r = e >> 2, slot = e & 3;
            int g = slot ^ ((r >> 1) & 3);
            gload16(W + (size_t)(n0 + r) * ldw + k0 + g * 8, &Ws[buf][e * 8]);
        }
    };

    f32x4 acc[FM][FN];
#pragma unroll
    for (int i = 0; i < FM; i++)
#pragma unroll
        for (int j = 0; j < FN; j++)
#pragma unroll
            for (int q = 0; q < 4; q++) acc[i][j][q] = 0.0f;

    stage(0, 0);
    __syncthreads();

    int nt = Ktot / 32;
    int cur = 0;
    for (int t = 0; t < nt; ++t) {
        if (t + 1 < nt) stage((t + 1) * 32, cur ^ 1);

        bf16x8 af[FM], bfr[FN];
#pragma unroll
        for (int mi = 0; mi < FM; mi++) {
            int r = wr * WM + mi * 16 + lr;
            int slot = lk ^ ((r >> 1) & 3);
            af[mi] = *reinterpret_cast<const bf16x8*>(&As[cur][r * 32 + slot * 8]);
        }
#pragma unroll
        for (int ni = 0; ni < FN; ni++) {
            int r = wc * WN + ni * 16 + lr;
            int slot = lk ^ ((r >> 1) & 3);
            bfr[ni] = *reinterpret_cast<const bf16x8*>(&Ws[cur][r * 32 + slot * 8]);
        }
#pragma unroll
        for (int mi = 0; mi < FM; mi++)
#pragma unroll
            for (int ni = 0; ni < FN; ni++)
                acc[mi][ni] = __builtin_amdgcn_mfma_f32_16x16x32_bf16(af[mi], bfr[ni], acc[mi][ni], 0, 0, 0);

        __syncthreads();
        cur ^= 1;
    }

    // epilogue: C/D layout col=lane&15, row=(lane>>4)*4+reg
#pragma unroll
    for (int mi = 0; mi < FM; mi++) {
#pragma unroll
        for (int ni = 0; ni < FN; ni++) {
            int col = n0 + wc * WN + ni * 16 + lr;
            if (col >= Nr) continue;
#pragma unroll
            for (int i = 0; i < 4; i++) {
                int row = m0 + wr * WM + mi * 16 + lk * 4 + i;
                size_t idx = (size_t)row * ldc + col;
                float v = acc[mi][ni][i];
                if constexpr (EPI == 0) {
                    C[idx] = (TC)v;
                } else if constexpr (EPI == 1) {
                    C[idx] += v;
                } else {
                    float s = v + bias[col];
                    C[idx] = (TC)((s > 20.0f) ? s : __logf(1.0f + __expf(s)));
                }
            }
        }
    }
}

// ---------------- x_proj split-K reduce (also emits bf16 dt-input copy) -----
__global__ void xproj_reduce_k(const float* __restrict__ part, float* __restrict__ xdbl,
                               bf16_t* __restrict__ xdt) {
    int idx = blockIdx.x * blockDim.x + threadIdx.x;
    if (idx >= M * XDW) return;
    int m = idx / XDW, j = idx % XDW;
    float s = 0.f;
#pragma unroll
    for (int sp = 0; sp < XSK; sp++) s += part[((size_t)sp * M + m) * 64 + j];
    xdbl[idx] = s;
    if (j < DTR) xdt[(size_t)m * DTR + j] = (bf16_t)s;
}

// ---------------- causal depthwise conv (DC=4) + SiLU, 8 channels/thread ----
__global__ __launch_bounds__(256) void conv_silu_k(const bf16_t* __restrict__ xz,
                                                   const float* __restrict__ cw,
                                                   const float* __restrict__ cb,
                                                   bf16_t* __restrict__ uc) {
    int idx = blockIdx.x * blockDim.x + threadIdx.x;   // over M*DI/8
    if (idx >= M * DI / 8) return;
    int d8 = idx % (DI / 8);
    int m = idx / (DI / 8);
    int b = m / L, l = m % L;
    int d0 = d8 * 8;

    float acc[8];
    {
        float4 c0 = *reinterpret_cast<const float4*>(cb + d0);
        float4 c1 = *reinterpret_cast<const float4*>(cb + d0 + 4);
        acc[0] = c0.x; acc[1] = c0.y; acc[2] = c0.z; acc[3] = c0.w;
        acc[4] = c1.x; acc[5] = c1.y; acc[6] = c1.z; acc[7] = c1.w;
    }
    float4 w[8];
#pragma unroll
    for (int j = 0; j < 8; j++)
        w[j] = *reinterpret_cast<const float4*>(cw + (size_t)(d0 + j) * DC);

#pragma unroll
    for (int k = 0; k < DC; k++) {
        int ls = l + k - (DC - 1);
        if (ls < 0) continue;
        bf16x8 v = *reinterpret_cast<const bf16x8*>(xz + (size_t)(b * L + ls) * XZW + d0);
        float wk[8] = {w[0].x, w[1].x, w[2].x, w[3].x, w[4].x, w[5].x, w[6].x, w[7].x};
        if (k == 1) { wk[0]=w[0].y; wk[1]=w[1].y; wk[2]=w[2].y; wk[3]=w[3].y; wk[4]=w[4].y; wk[5]=w[5].y; wk[6]=w[6].y; wk[7]=w[7].y; }
        if (k == 2) { wk[0]=w[0].z; wk[1]=w[1].z; wk[2]=w[2].z; wk[3]=w[3].z; wk[4]=w[4].z; wk[5]=w[5].z; wk[6]=w[6].z; wk[7]=w[7].z; }
        if (k == 3) { wk[0]=w[0].w; wk[1]=w[1].w; wk[2]=w[2].w; wk[3]=w[3].w; wk[4]=w[4].w; wk[5]=w[5].w; wk[6]=w[6].w; wk[7]=w[7].w; }
#pragma unroll
        for (int j = 0; j < 8; j++) acc[j] += (float)v[j] * wk[j];
    }
    bf16x8 o;
#pragma unroll
    for (int j = 0; j < 8; j++) {
        float a = acc[j];
        o[j] = (bf16_t)(a / (1.0f + __expf(-a)));
    }
    *reinterpret_cast<bf16x8*>(uc + (size_t)m * DI + d0) = o;
}

// ---------------- selective scan, 3-phase chunked ---------------------------
// hpart/aprod layout: [b][c][d][n] (coalesced float4 along d)
__global__ __launch_bounds__(256) void scan_part_k(const bf16_t* __restrict__ dt,
                                                   const bf16_t* __restrict__ uc,
                                                   const float* __restrict__ xdbl,
                                                   const float* __restrict__ A_log,
                                                   float* __restrict__ hpart,
                                                   float* __restrict__ aprod) {
    int gid = blockIdx.x * 256 + threadIdx.x;
    if (gid >= B * NCH * DI) return;
    int d = gid % DI;
    int c = (gid / DI) % NCH;
    int b = gid / (DI * NCH);
    float Av[DS];
    {
        float4 a0 = *reinterpret_cast<const float4*>(A_log + d * DS);
        float4 a1 = *reinterpret_cast<const float4*>(A_log + d * DS + 4);
        Av[0] = -__expf(a0.x); Av[1] = -__expf(a0.y); Av[2] = -__expf(a0.z); Av[3] = -__expf(a0.w);
        Av[4] = -__expf(a1.x); Av[5] = -__expf(a1.y); Av[6] = -__expf(a1.z); Av[7] = -__expf(a1.w);
    }
    float h[DS] = {};
    float ap[DS];
#pragma unroll
    for (int n = 0; n < DS; n++) ap[n] = 1.0f;
    int l0 = c * CH;
    for (int t = 0; t < CH; t++) {
        size_t row = (size_t)b * L + l0 + t;
        float dtv = (float)dt[row * DI + d];
        float uv = (float)uc[row * DI + d];
        const float4* xr4 = reinterpret_cast<const float4*>(xdbl + row * XDW + DTR);
        float4 b0 = xr4[0], b1 = xr4[1];
        float Bv[DS] = {b0.x, b0.y, b0.z, b0.w, b1.x, b1.y, b1.z, b1.w};
        float du = dtv * uv;
#pragma unroll
        for (int n = 0; n < DS; n++) {
            float dA = __expf(dtv * Av[n]);
            h[n] = dA * h[n] + du * Bv[n];
            ap[n] *= dA;
        }
    }
    size_t base = (((size_t)(b * NCH + c) * DI) + d) * DS;
    f32x4* hp4 = reinterpret_cast<f32x4*>(hpart + base);
    f32x4* ap4 = reinterpret_cast<f32x4*>(aprod + base);
    f32x4 v0, v1, w0, w1;
#pragma unroll
    for (int n = 0; n < 4; n++) { v0[n] = h[n]; v1[n] = h[n + 4]; w0[n] = ap[n]; w1[n] = ap[n + 4]; }
    hp4[0] = v0; hp4[1] = v1;
    ap4[0] = w0; ap4[1] = w1;
}

// per (b,d,n) sequential combine over chunks; hpart[c] := state BEFORE chunk c
__global__ void scan_combine_k(float* __restrict__ hpart, const float* __restrict__ aprod) {
    int gid = blockIdx.x * blockDim.x + threadIdx.x;
    if (gid >= B * DI * DS) return;
    int dn = gid & (DI * DS - 1);      // (d,n) combined: consecutive lanes coalesced
    int b = gid >> 13;
    float hrun = 0.f;
    for (int c = 0; c < NCH; c++) {
        size_t idx = ((size_t)(b * NCH + c) * DI * DS) + dn;
        float ap = aprod[idx];
        float hp = hpart[idx];
        hpart[idx] = hrun;
        hrun = ap * hrun + hp;
    }
}

__global__ __launch_bounds__(256) void scan_emit_k(const bf16_t* __restrict__ dt,
                                                   const bf16_t* __restrict__ uc,
                                                   const float* __restrict__ xdbl,
                                                   const bf16_t* __restrict__ xz,
                                                   const float* __restrict__ A_log,
                                                   const float* __restrict__ Dp,
                                                   const float* __restrict__ hpart,
                                                   bf16_t* __restrict__ y) {
    int gid = blockIdx.x * 256 + threadIdx.x;
    if (gid >= B * NCH * DI) return;
    int d = gid % DI;
    int c = (gid / DI) % NCH;
    int b = gid / (DI * NCH);
    float Av[DS];
    {
        float4 a0 = *reinterpret_cast<const float4*>(A_log + d * DS);
        float4 a1 = *reinterpret_cast<const float4*>(A_log + d * DS + 4);
        Av[0] = -__expf(a0.x); Av[1] = -__expf(a0.y); Av[2] = -__expf(a0.z); Av[3] = -__expf(a0.w);
        Av[4] = -__expf(a1.x); Av[5] = -__expf(a1.y); Av[6] = -__expf(a1.z); Av[7] = -__expf(a1.w);
    }
    float h[DS];
    {
        size_t base = (((size_t)(b * NCH + c) * DI) + d) * DS;
        const f32x4* hp4 = reinterpret_cast<const f32x4*>(hpart + base);
        f32x4 v0 = hp4[0], v1 = hp4[1];
#pragma unroll
        for (int n = 0; n < 4; n++) { h[n] = v0[n]; h[n + 4] = v1[n]; }
    }
    float Dv = Dp[d];
    int l0 = c * CH;
    for (int t = 0; t < CH; t++) {
        size_t row = (size_t)b * L + l0 + t;
        float dtv = (float)dt[row * DI + d];
        float uv = (float)uc[row * DI + d];
        const float4* xr4 = reinterpret_cast<const float4*>(xdbl + row * XDW + DTR);
        float4 b0 = xr4[0], b1 = xr4[1], c0 = xr4[2], c1 = xr4[3];
        float Bv[DS] = {b0.x, b0.y, b0.z, b0.w, b1.x, b1.y, b1.z, b1.w};
        float Cv[DS] = {c0.x, c0.y, c0.z, c0.w, c1.x, c1.y, c1.z, c1.w};
        float du = dtv * uv;
        float yv = 0.f;
#pragma unroll
        for (int n = 0; n < DS; n++) {
            float dA = __expf(dtv * Av[n]);
            h[n] = dA * h[n] + du * Bv[n];
            yv += h[n] * Cv[n];
        }
        yv += uv * Dv;
        float zv = (float)xz[row * XZW + DI + d];
        yv *= zv / (1.0f + __expf(-zv));
        y[row * DI + d] = (bf16_t)yv;
    }
}

// ---------------- mean over L (2-stage), then head --------------------------
// partial layout: [b][c*4+rsub][DM]
__global__ __launch_bounds__(256) void mean_part_k(const bf16_t* __restrict__ hn,
                                                   float* __restrict__ partial) {
    int c = blockIdx.x;   // 32 chunks of 64 rows
    int b = blockIdx.y;
    int t = threadIdx.x;
    int d0 = (t & 63) * 8;
    int rsub = t >> 6;    // 4 row subsets
    float s[8] = {};
    for (int l = rsub; l < 64; l += 4) {
        bf16x8 v = *reinterpret_cast<const bf16x8*>(hn + (size_t)(b * L + c * 64 + l) * DM + d0);
#pragma unroll
        for (int j = 0; j < 8; j++) s[j] += (float)v[j];
    }
    float* dst = partial + ((size_t)(b * 32 + c) * 4 + rsub) * DM + d0;
    f32x4 o0, o1;
#pragma unroll
    for (int j = 0; j < 4; j++) { o0[j] = s[j]; o1[j] = s[j + 4]; }
    reinterpret_cast<f32x4*>(dst)[0] = o0;
    reinterpret_cast<f32x4*>(dst)[1] = o1;
}

__global__ void mean_fin_k(const float* __restrict__ partial, float* __restrict__ hmean) {
    int idx = blockIdx.x * blockDim.x + threadIdx.x;
    if (idx >= B * DM) return;
    int b = idx / DM, d = idx % DM;
    float s = 0.f;
    for (int c = 0; c < 128; c++) s += partial[((size_t)b * 128 + c) * DM + d];
    hmean[idx] = s * (1.0f / L);
}

__global__ void head_k(const float* __restrict__ hmean, const float* __restrict__ hw,
                       const float* __restrict__ hb, float* __restrict__ out) {
    int t = threadIdx.x;
    if (t >= B * NC) return;
    int b = t / NC, c = t % NC;
    float acc = hb[c];
    for (int k = 0; k < DM; k++) acc += hmean[b * DM + k] * hw[c * DM + k];
    out[t] = acc;
}

extern "C" void kernel_launch(void* const* d_in, const int* in_sizes, int n_in,
                              void* d_out, int out_size, void* d_ws, size_t ws_size,
                              hipStream_t stream) {
    const float* x      = (const float*)d_in[0];
    const float* inp_w  = (const float*)d_in[1];
    const float* inp_b  = (const float*)d_in[2];
    const float* norm_g = (const float*)d_in[3];
    const float* norm_b = (const float*)d_in[4];
    const float* in_w   = (const float*)d_in[5];
    const float* conv_w = (const float*)d_in[6];
    const float* conv_b = (const float*)d_in[7];
    const float* xp_w   = (const float*)d_in[8];
    const float* dt_w   = (const float*)d_in[9];
    const float* dt_b   = (const float*)d_in[10];
    const float* A_log  = (const float*)d_in[11];
    const float* Dp     = (const float*)d_in[12];
    const float* out_w  = (const float*)d_in[13];
    const float* fnorm_g = (const float*)d_in[14];
    const float* fnorm_b = (const float*)d_in[15];
    const float* head_w = (const float*)d_in[16];
    const float* head_b = (const float*)d_in[17];
    float* out = (float*)d_out;

    char* p = (char*)d_ws;
    float*  h     = (float*)p;  p += (size_t)M * DM * 4;
    bf16_t* hn    = (bf16_t*)p; p += (size_t)M * DM * 2;
    bf16_t* xz    = (bf16_t*)p; p += (size_t)M * XZW * 2;
    bf16_t* uc    = (bf16_t*)p; p += (size_t)M * DI * 2;
    float*  xdbl  = (float*)p;  p += (size_t)M * XDW * 4;
    bf16_t* xdt   = (bf16_t*)p; p += (size_t)M * DTR * 2;
    bf16_t* dtb   = (bf16_t*)p; p += (size_t)M * DI * 2;
    bf16_t* yb    = (bf16_t*)p; p += (size_t)M * DI * 2;
    float*  hpart = (float*)p;  p += (size_t)B * DI * NCH * DS * 4;
    float*  aprod = (float*)p;  p += (size_t)B * DI * NCH * DS * 4;
    float*  xpart = (float*)p;  p += (size_t)XSK * M * 64 * 4;
    float*  partial = (float*)p; p += (size_t)B * 128 * DM * 4;
    float*  hmean = (float*)p;  p += (size_t)B * DM * 4;
    bf16_t* wb_in = (bf16_t*)p; p += (size_t)NL * XZW * DM * 2;
    bf16_t* wb_xp = (bf16_t*)p; p += (size_t)NL * XPR * DI * 2;
    bf16_t* wb_dt = (bf16_t*)p; p += (size_t)NL * DI * DTR * 2;
    bf16_t* wb_out = (bf16_t*)p; p += (size_t)NL * DM * DI * 2;

    // weights -> bf16 (once per call; x_proj padded to 64 rows with zeros)
    cvt_ws_k<<<(WNTp + 255) / 256, 256, 0, stream>>>(in_w, xp_w, dt_w, out_w,
                                                     wb_in, wb_xp, wb_dt, wb_out);
    // embed + layer-0 LN fused
    embed_ln_k<<<M, 256, 0, stream>>>(x, inp_w, inp_b, norm_g, norm_b, h, hn);

    for (int i = 0; i < NL; i++) {
        const bf16_t* inw_i = wb_in + (size_t)i * XZW * DM;
        const float* cw_i  = conv_w + (size_t)i * DI * DC;
        const float* cb_i  = conv_b + (size_t)i * DI;
        const bf16_t* xpw_i = wb_xp + (size_t)i * XPR * DI;
        const bf16_t* dtw_i = wb_dt + (size_t)i * DI * DTR;
        const float* dtb_i = dt_b + (size_t)i * DI;
        const float* Al_i  = A_log + (size_t)i * DI * DS;
        const float* Dp_i  = Dp + (size_t)i * DI;
        const bf16_t* ow_i  = wb_out + (size_t)i * DM * DI;

        // hn = LN(h) -> bf16 (layer 0 already done by embed_ln_k)
        if (i > 0)
            layernorm_k<<<M, 256, 0, stream>>>(h, norm_g + i * DM, norm_b + i * DM, hn);
        // xz = hn @ in_w^T   (M x 2048, K=512), 128x128 tiles -> 1024 blocks
        gemm_mfma<128, 128, 0, bf16_t, 1><<<dim3(XZW / 128, M / 128), 256, 0, stream>>>(
            hn, DM, inw_i, DM, nullptr, xz, XZW, XZW, DM);
        // uc = silu(conv(u)), 8 ch/thread
        conv_silu_k<<<(M * DI / 8 + 255) / 256, 256, 0, stream>>>(xz, cw_i, cb_i, uc);
        // xdbl = uc @ xp_w^T  (M x 48, K=1024) split-K=8 -> partials, then reduce
        gemm_mfma<64, 64, 0, float, XSK><<<dim3(1, M / 64, XSK), 256, 0, stream>>>(
            uc, DI, xpw_i, DI, nullptr, xpart, 64, XDW, DI);
        xproj_reduce_k<<<(M * XDW + 255) / 256, 256, 0, stream>>>(xpart, xdbl, xdt);
        // dt = softplus(xdt @ dt_w^T + dt_b)  (M x 1024, K=32)
        gemm_mfma<64, 64, 2, bf16_t, 1><<<dim3(DI / 64, M / 64), 256, 0, stream>>>(
            xdt, DTR, dtw_i, DTR, dtb_i, dtb, DI, DI, DTR);
        // selective scan (chunked), fused gate + u*D
        scan_part_k<<<(B * NCH * DI) / 256, 256, 0, stream>>>(dtb, uc, xdbl, Al_i, hpart, aprod);
        scan_combine_k<<<(B * DI * DS + 255) / 256, 256, 0, stream>>>(hpart, aprod);
        scan_emit_k<<<(B * NCH * DI) / 256, 256, 0, stream>>>(dtb, uc, xdbl, xz, Al_i, Dp_i, hpart, yb);
        // h += y @ out_w^T  (M x 512, K=1024), 64x64 tiles -> 1024 blocks
        gemm_mfma<64, 64, 1, float, 1><<<dim3(DM / 64, M / 64), 256, 0, stream>>>(
            yb, DI, ow_i, DI, nullptr, h, DM, DM, DI);
    }

    // final LN -> mean over L (2-stage) -> head
    layernorm_k<<<M, 256, 0, stream>>>(h, fnorm_g, fnorm_b, hn);
    mean_part_k<<<dim3(32, B), 256, 0, stream>>>(hn, partial);
    mean_fin_k<<<(B * DM + 255) / 256, 256, 0, stream>>>(partial, hmean);
    head_k<<<1, 256, 0, stream>>>(hmean, head_w, head_b, out);
}